// Round 5
// baseline (2864.032 us; speedup 1.0000x reference)
//
#include <hip/hip_runtime.h>
#include <math.h>

#define CB 64      // batch
#define CT 1024    // time
#define CCH 12     // channels
#define CD 512     // d_model
#define CL 2       // layers
#define CFFN 2048
#define CFCH 256
#define CNC 5
#define CTOPK 20
#define CEPS 1e-5f

typedef __attribute__((ext_vector_type(8))) short bfrag;
typedef __attribute__((ext_vector_type(4))) float ffrag;

__device__ inline ushort bf16r(float f) {
  unsigned u = __float_as_uint(f);
  unsigned r = (u + 0x7FFFu + ((u >> 16) & 1u)) >> 16;
  return (ushort)r;
}
__device__ inline float bf16f(ushort h) { return __uint_as_float(((unsigned)h) << 16); }

// async 16B global->LDS (lds dest = wave-uniform base + lane*16)
__device__ __forceinline__ void gld16(const ushort* g, ushort* l) {
  __builtin_amdgcn_global_load_lds((__attribute__((address_space(1))) void*)g,
                                   (__attribute__((address_space(3))) void*)l,
                                   16, 0, 0);
}

// ---------------- complex helpers ----------------
struct c32 { float x, y; };
__device__ inline c32 cadd(c32 a, c32 b) { return c32{a.x + b.x, a.y + b.y}; }
__device__ inline c32 csub(c32 a, c32 b) { return c32{a.x - b.x, a.y - b.y}; }
__device__ inline c32 cmul(c32 a, c32 b) {  // a*b
  return c32{a.x * b.x - a.y * b.y, a.x * b.y + a.y * b.x};
}
__device__ inline c32 cmulj(c32 a, c32 b) {  // a*conj(b)
  return c32{a.x * b.x + a.y * b.y, a.y * b.x - a.x * b.y};
}
__device__ inline c32 mineg_i(c32 a) { return c32{a.y, -a.x}; }  // -i*a
__device__ inline c32 mul_i(c32 a) { return c32{-a.y, a.x}; }    // +i*a

// LDS padding: +1 c32 per 16 -> balanced 4-way (wave64 minimum) on every
// stage stride and on the digit-reversed scatter.
#define ZIDX(p) ((p) + ((p) >> 4))

// base-4 digit reversal of 5 digits (N=1024=4^5); involution
__device__ inline int drev4(int t) {
  return ((t & 3) << 8) | (((t >> 2) & 3) << 6) | (((t >> 4) & 3) << 4) |
         (((t >> 6) & 3) << 2) | ((t >> 8) & 3);
}

// radix-4 DIT stage s (in-place; input digit-reversed, output natural).
template <int INV>
__device__ inline void fft_stage(c32* zz, const c32* twl, int tid, int s) {
  int L = 1 << (2 * s);
  int j = tid & (L - 1);
  int g = tid >> (2 * s);
  int p0 = (g << (2 * s + 2)) + j;
  int tb = j << (8 - 2 * s);
  c32 w1 = twl[ZIDX(tb)], w2 = twl[ZIDX(2 * tb)], w3 = twl[ZIDX(3 * tb)];
  c32 b0 = zz[ZIDX(p0)], b1 = zz[ZIDX(p0 + L)], b2 = zz[ZIDX(p0 + 2 * L)],
      b3 = zz[ZIDX(p0 + 3 * L)];
  if (INV) { b1 = cmulj(b1, w1); b2 = cmulj(b2, w2); b3 = cmulj(b3, w3); }
  else     { b1 = cmul(b1, w1);  b2 = cmul(b2, w2);  b3 = cmul(b3, w3); }
  c32 e0 = cadd(b0, b2), e1 = csub(b0, b2), e2 = cadd(b1, b3), e3 = csub(b1, b3);
  c32 e3r = INV ? mul_i(e3) : mineg_i(e3);
  zz[ZIDX(p0)] = cadd(e0, e2);
  zz[ZIDX(p0 + L)] = cadd(e1, e3r);
  zz[ZIDX(p0 + 2 * L)] = csub(e0, e2);
  zz[ZIDX(p0 + 3 * L)] = csub(e1, e3r);
}

// unpack packed-real FFT (z=q+ik, ZIDX-padded) at bin w; accumulate P = Qf*conj(Kf)
__device__ inline void unp_acc(const c32* zf, int w, c32& acc) {
  int wc = (1024 - w) & 1023;
  c32 Z1 = zf[ZIDX(w)];
  c32 Z2r = zf[ZIDX(wc)];
  c32 Z2 = c32{Z2r.x, -Z2r.y};                       // conj(Z[N-w])
  c32 Qf = c32{0.5f * (Z1.x + Z2.x), 0.5f * (Z1.y + Z2.y)};
  c32 M = c32{Z1.x - Z2.x, Z1.y - Z2.y};
  c32 Kf = c32{0.5f * M.y, -0.5f * M.x};             // -0.5i*M
  acc.x += Qf.x * Kf.x + Qf.y * Kf.y;                // Qf*conj(Kf)
  acc.y += Qf.y * Kf.x - Qf.x * Kf.y;
}

// ---------------- twiddle table, fp64-accurate (one-time) ---------------------------
__global__ __launch_bounds__(256) void k_twid(c32* __restrict__ tw) {
  int j = blockIdx.x * 256 + threadIdx.x;  // 0..1023
  double a = -2.0 * 3.14159265358979323846 * (double)j / 1024.0;
  tw[j] = c32{(float)cos(a), (float)sin(a)};
}

// ---------------- mean-abs scaler ----------------
__global__ __launch_bounds__(256) void k_scale(const float* __restrict__ x,
                                               float* __restrict__ sc,
                                               float* __restrict__ lg) {
  int b = blockIdx.x, tid = threadIdx.x;
  float acc[CCH];
#pragma unroll
  for (int c = 0; c < CCH; ++c) acc[c] = 0.f;
  const float* xb = x + (size_t)b * CT * CCH;
  for (int t = tid; t < CT; t += 256) {
    const float* row = xb + t * CCH;
#pragma unroll
    for (int c = 0; c < CCH; ++c) acc[c] += fabsf(row[c]);
  }
  __shared__ float red[256][CCH];
#pragma unroll
  for (int c = 0; c < CCH; ++c) red[tid][c] = acc[c];
  __syncthreads();
  for (int off = 128; off > 0; off >>= 1) {
    if (tid < off) {
#pragma unroll
      for (int c = 0; c < CCH; ++c) red[tid][c] += red[tid + off][c];
    }
    __syncthreads();
  }
  if (tid < CCH) {
    float s = fmaxf(red[0][tid] * (1.0f / CT), 1e-10f);
    sc[b * CCH + tid] = s;
    lg[b * CCH + tid] = logf(s);
  }
}

// ---------------- sinusoidal position table (f64, matches np) ----------------
__global__ __launch_bounds__(512) void k_postab(float* __restrict__ pos) {
  int t = blockIdx.x;
  int d = threadIdx.x;
  double v;
  if (d < 256) {
    double w = pow(10000.0, -((double)d) / 256.0);
    v = sin((double)t * w);
  } else {
    double w = pow(10000.0, -((double)(d - 256)) / 256.0);
    v = cos((double)t * w);
  }
  pos[(size_t)t * CD + d] = (float)v;
}

// ---------------- embedding + LN fused; writes fp32 h AND bf16 h2 -------------------
__global__ __launch_bounds__(128) void k_embed(const float* __restrict__ x,
                                               const float* __restrict__ sc,
                                               const float* __restrict__ lg,
                                               const float* __restrict__ W,
                                               const float* __restrict__ postab,
                                               const float* __restrict__ g,
                                               const float* __restrict__ beta,
                                               float* __restrict__ h,
                                               ushort* __restrict__ h2) {
  int row = blockIdx.x;  // local: b*T + t
  int b = row >> 10, t = row & 1023;
  int tid = threadIdx.x;
  __shared__ float xs[CCH], ls[CCH];
  if (tid < CCH) {
    float s = sc[b * CCH + tid];
    xs[tid] = x[(size_t)row * CCH + tid] / s;
    ls[tid] = lg[b * CCH + tid];
  }
  __syncthreads();
  int d0 = tid * 4;
  float4 p = *(const float4*)(postab + (size_t)t * CD + d0);
  float v0 = p.x, v1 = p.y, v2 = p.z, v3 = p.w;
#pragma unroll
  for (int c = 0; c < CCH; ++c) {
    float xc = xs[c], lc = ls[c];
    float4 w0 = *(const float4*)(W + (size_t)c * CD + d0);
    float4 w1 = *(const float4*)(W + (size_t)(24 + c) * CD + d0);
    v0 += xc * w0.x + lc * w1.x;
    v1 += xc * w0.y + lc * w1.y;
    v2 += xc * w0.z + lc * w1.z;
    v3 += xc * w0.w + lc * w1.w;
  }
  float s1 = v0 + v1 + v2 + v3;
  float s2 = v0 * v0 + v1 * v1 + v2 * v2 + v3 * v3;
  for (int off = 32; off > 0; off >>= 1) {
    s1 += __shfl_down(s1, off);
    s2 += __shfl_down(s2, off);
  }
  __shared__ float ws1[2], ws2[2], mv[2];
  int wid = tid >> 6, lane = tid & 63;
  if (lane == 0) { ws1[wid] = s1; ws2[wid] = s2; }
  __syncthreads();
  if (tid == 0) {
    float S1 = ws1[0] + ws1[1], S2 = ws2[0] + ws2[1];
    float mu = S1 * (1.0f / CD);
    float var = S2 * (1.0f / CD) - mu * mu;
    mv[0] = mu;
    mv[1] = 1.0f / sqrtf(var + CEPS);
  }
  __syncthreads();
  float mu = mv[0], ri = mv[1];
  float4 gg = *(const float4*)(g + d0);
  float4 bb = *(const float4*)(beta + d0);
  float4 o;
  o.x = (v0 - mu) * ri * gg.x + bb.x;
  o.y = (v1 - mu) * ri * gg.y + bb.y;
  o.z = (v2 - mu) * ri * gg.z + bb.z;
  o.w = (v3 - mu) * ri * gg.w + bb.w;
  *(float4*)(h + (size_t)row * CD + d0) = o;
  ushort4 hv = {bf16r(o.x), bf16r(o.y), bf16r(o.z), bf16r(o.w)};
  *(ushort4*)(h2 + (size_t)row * CD + d0) = hv;
}

// ---------------- weight convert+transpose: W[K][N] fp32 -> W2[N][K] bf16 -----------
// blockIdx.z batches multiple same-shape matrices (stride K*N on both sides).
__global__ __launch_bounds__(256) void k_cvtw(const float* __restrict__ W,
                                              ushort* __restrict__ W2,
                                              int K, int N) {
  __shared__ float tile[32][33];
  size_t zoff = (size_t)blockIdx.z * K * N;
  int tx = threadIdx.x & 31, ty = threadIdx.x >> 5;  // ty 0..7
  int n0 = blockIdx.x * 32, k0 = blockIdx.y * 32;
#pragma unroll
  for (int r = 0; r < 4; ++r)
    tile[ty * 4 + r][tx] = W[zoff + (size_t)(k0 + ty * 4 + r) * N + n0 + tx];
  __syncthreads();
#pragma unroll
  for (int r = 0; r < 4; ++r) {
    int nl = ty * 4 + r, kl = tx;
    W2[zoff + (size_t)(n0 + nl) * K + k0 + kl] = bf16r(tile[kl][nl]);
  }
}

// ---------------- bf16 MFMA GEMM, 128x128 tile, BK=32, double-buffered pipeline -----
// A: [M][lda] bf16 k-contig rows; W: [N][ldb] bf16 k-contig rows.
// LDS chunk swizzle: chunk q of row r at slot q^((r>>2)&3) -> 2-way bank access (free).
// Pipeline: prefetch distance 2; per-iter wait `s_waitcnt vmcnt(4)`.  (Depth-3 A/B'd
// in R3: regressed; reverted. XCD swizzle kept: FETCH 68.8->33MB.)
// __launch_bounds__(256,4): R4 showed reg-limit (80V+64A=144) caps 3 waves/SIMD,
// Occupancy 27%; forcing 4 waves/SIMD adds TLP to cover the barrier drain.
// Grid: XCD-chunked bijective swizzle of the flat block id (nwg always %8==0 here).
// EPI: 0=bias->fp32  1=bias+GELU->bf16  2=bias+residual->fp32
//      3=bias+residual->fp32 + per-row LN-stats partials (Cs2 = st8[M][8] c32)
//      7=QKV: cols<1024 -> TRANSPOSED fp32 Cf[col][ldc] (ldc=Mc, time-contig for FFT),
//             cols>=1024 -> V bf16 [row][512] via Cs pointer
template <int EPI>
__global__ __launch_bounds__(256, 4) void k_gemm3(const ushort* __restrict__ A,
                                                  const ushort* __restrict__ W,
                                                  const float* __restrict__ bias,
                                                  const float* __restrict__ R,
                                                  float* __restrict__ Cf,
                                                  ushort* __restrict__ Cs,
                                                  ushort* __restrict__ Cs2,
                                                  int lda, int ldb, int ldc, int K) {
  __shared__ ushort AhS[2][128 * 32];
  __shared__ ushort BhS[2][128 * 32];
  int tid = threadIdx.x;
  // XCD-chunked bijective remap of flat block id (x fastest in dispatch order)
  int nx = gridDim.x;
  int nwg = nx * gridDim.y;
  int flat = blockIdx.y * nx + blockIdx.x;
  int sw = (flat & 7) * (nwg >> 3) + (flat >> 3);
  int n0 = (sw % nx) * 128, m0 = (sw / nx) * 128;
  int wid = __builtin_amdgcn_readfirstlane(tid >> 6);
  int lane = tid & 63;
  int lr = lane >> 2;                              // 0..15: row in a 16-row gld16 group
  int lc = ((lane & 3) ^ ((lr >> 2) & 3)) * 8;     // swizzled source chunk (ushorts)
  int wm = wid >> 1, wn = wid & 1;
  int mOff = wm * 64, nOff = wn * 64;
  int quad = lane >> 4, l16 = lane & 15;

  const ushort* pA = A + (size_t)(m0 + wid * 32 + lr) * lda + lc;
  const ushort* pB = W + (size_t)(n0 + wid * 32 + lr) * ldb + lc;
  const int NK = K >> 5;

  ffrag acc[4][4];
#pragma unroll
  for (int i = 0; i < 4; ++i)
#pragma unroll
    for (int j = 0; j < 4; ++j) acc[i][j] = (ffrag)(0.f);

#define ISSUE(t, buf)                                                        \
  {                                                                          \
    int kk = (t) << 5;                                                       \
    ushort* lA = &AhS[buf][(wid * 32) * 32];                                 \
    ushort* lB = &BhS[buf][(wid * 32) * 32];                                 \
    gld16(pA + kk, lA);                                                      \
    gld16(pA + (size_t)16 * lda + kk, lA + 16 * 32);                         \
    gld16(pB + kk, lB);                                                      \
    gld16(pB + (size_t)16 * ldb + kk, lB + 16 * 32);                         \
  }

  ISSUE(0, 0);
  ISSUE(1, 1);
  for (int k = 0; k < NK; ++k) {
    if (k + 1 < NK) {
      asm volatile("s_waitcnt vmcnt(4)\n\ts_barrier" ::: "memory");
    } else {
      asm volatile("s_waitcnt vmcnt(0)\n\ts_barrier" ::: "memory");
    }
    int buf = k & 1;
    bfrag ah[4], bh[4];
#pragma unroll
    for (int i = 0; i < 4; ++i) {
      int row = mOff + i * 16 + l16;
      ah[i] = *(const bfrag*)&AhS[buf][row * 32 + (quad ^ ((row >> 2) & 3)) * 8];
    }
#pragma unroll
    for (int j = 0; j < 4; ++j) {
      int row = nOff + j * 16 + l16;
      bh[j] = *(const bfrag*)&BhS[buf][row * 32 + (quad ^ ((row >> 2) & 3)) * 8];
    }
#pragma unroll
    for (int i = 0; i < 4; ++i)
#pragma unroll
      for (int j = 0; j < 4; ++j)
        acc[i][j] = __builtin_amdgcn_mfma_f32_16x16x32_bf16(ah[i], bh[j], acc[i][j], 0, 0, 0);
    asm volatile("s_barrier" ::: "memory");
    if (k + 2 < NK) ISSUE(k + 2, buf);
  }
#undef ISSUE

  // C tile layout: col = lane&15, row = quad*4 + reg (verified R3-R10)
  if (EPI == 3) {
    // row-major epilogue: residual add + store + per-row stats partial
    c32* st8 = (c32*)Cs2;
#pragma unroll
    for (int i = 0; i < 4; ++i) {
#pragma unroll
      for (int r = 0; r < 4; ++r) {
        int row = m0 + mOff + i * 16 + quad * 4 + r;
        float s1 = 0.f, s2 = 0.f;
#pragma unroll
        for (int j = 0; j < 4; ++j) {
          int col = n0 + nOff + j * 16 + l16;
          float vv = acc[i][j][r] + bias[col] + R[(size_t)row * ldc + col];
          Cf[(size_t)row * ldc + col] = vv;
          s1 += vv;
          s2 += vv * vv;
        }
        // reduce across the 16 lanes (l16) of this quad: xor tree stays in-group
#pragma unroll
        for (int off = 8; off > 0; off >>= 1) {
          s1 += __shfl_xor(s1, off);
          s2 += __shfl_xor(s2, off);
        }
        if (l16 == 0) st8[(size_t)row * 8 + (n0 >> 6) + wn] = c32{s1, s2};
      }
    }
  } else {
#pragma unroll
    for (int j = 0; j < 4; ++j) {
      int col = n0 + nOff + j * 16 + l16;
      float bcol = bias[col];
#pragma unroll
      for (int i = 0; i < 4; ++i) {
        int rowb = m0 + mOff + i * 16 + quad * 4;
        if (EPI == 7) {
          if (col < 1024) {
            float4 o = {acc[i][j][0] + bcol, acc[i][j][1] + bcol,
                        acc[i][j][2] + bcol, acc[i][j][3] + bcol};
            *(float4*)(Cf + (size_t)col * ldc + rowb) = o;  // transposed, 16B-aligned
          } else {
#pragma unroll
            for (int r = 0; r < 4; ++r)
              Cs[(size_t)(rowb + r) * 512 + (col - 1024)] = bf16r(acc[i][j][r] + bcol);
          }
        } else {
#pragma unroll
          for (int r = 0; r < 4; ++r) {
            int row = rowb + r;
            float vv = acc[i][j][r] + bcol;
            if (EPI == 1) vv = 0.5f * vv * (1.0f + erff(vv * 0.7071067811865475f));
            if (EPI == 2) vv += R[(size_t)row * ldc + col];
            if (EPI == 1) {
              Cs[(size_t)row * ldc + col] = bf16r(vv);
            } else {
              Cf[(size_t)row * ldc + col] = vv;
            }
          }
        }
      }
    }
  }
}

// ---------------- combine st8 partials -> (mu, 1/sigma) per row ---------------------
__global__ __launch_bounds__(256) void k_finst(const c32* __restrict__ st8,
                                               c32* __restrict__ st) {
  int row = blockIdx.x * 256 + threadIdx.x;
  float s1 = 0.f, s2 = 0.f;
#pragma unroll
  for (int p = 0; p < 8; ++p) {
    c32 v = st8[(size_t)row * 8 + p];
    s1 += v.x;
    s2 += v.y;
  }
  float mu = s1 * (1.0f / CD);
  float var = s2 * (1.0f / CD) - mu * mu;
  st[row] = c32{mu, 1.0f / sqrtf(var + CEPS)};
}

// ---------------- autocorrelation via packed-real FFT (transposed input) ------------
__global__ __launch_bounds__(256) void k_fft(const float* __restrict__ QT,
                                             const c32* __restrict__ twg,
                                             c32* __restrict__ part, int Mc) {
  __shared__ c32 z[4][1088];
  __shared__ c32 twl[1088];
  int dg = blockIdx.x, zb = blockIdx.y, tid = threadIdx.x;
#pragma unroll
  for (int k = 0; k < 4; ++k) {
    int i = tid + k * 256;
    twl[ZIDX(i)] = twg[i];
  }
  c32 pa = {0.f, 0.f}, pb = {0.f, 0.f}, p5 = {0.f, 0.f};
  for (int i = 0; i < 4; ++i) {
    int d0 = dg * 16 + i * 4;
#pragma unroll
    for (int f = 0; f < 4; ++f) {
      const float* qr = QT + (size_t)(d0 + f) * Mc + (size_t)zb * 1024;
      const float* kr = QT + (size_t)(512 + d0 + f) * Mc + (size_t)zb * 1024;
#pragma unroll
      for (int k = 0; k < 4; ++k) {
        int t = tid + k * 256;
        z[f][ZIDX(drev4(t))] = c32{qr[t], kr[t]};
      }
    }
    __syncthreads();  // also covers twl on first iter
    for (int s = 0; s < 5; ++s) {
#pragma unroll
      for (int f = 0; f < 4; ++f) fft_stage<0>(&z[f][0], twl, tid, s);
      __syncthreads();
    }
#pragma unroll
    for (int f = 0; f < 4; ++f) {
      unp_acc(&z[f][0], tid, pa);
      unp_acc(&z[f][0], tid + 256, pb);
      if (tid == 0) unp_acc(&z[f][0], 512, p5);
    }
    __syncthreads();  // before next iter overwrites z
  }
  c32* po = part + ((size_t)zb * 32 + dg) * 513;
  po[tid] = pa;
  po[tid + 256] = pb;
  if (tid == 0) po[512] = p5;
}

// ---------------- spectrum reduce + irfft + top-20 + softmax (fused) ----------------
__global__ __launch_bounds__(256) void k_spectopk(const c32* __restrict__ part,
                                                  const c32* __restrict__ twg,
                                                  float* __restrict__ wts,
                                                  int* __restrict__ idxs) {
  int b = blockIdx.x, tid = threadIdx.x;
  __shared__ c32 twl[1088];
  __shared__ c32 S[1024];
  __shared__ c32 zz[1088];
  __shared__ float corr[1024];
#pragma unroll
  for (int k = 0; k < 4; ++k) {
    int i = tid + k * 256;
    twl[ZIDX(i)] = twg[i];
  }
  c32 sa = {0.f, 0.f}, sb = {0.f, 0.f}, s5 = {0.f, 0.f};
  const c32* pbase = part + (size_t)b * 32 * 513;
  for (int p = 0; p < 32; ++p) {
    const c32* pp = pbase + p * 513;
    sa = cadd(sa, pp[tid]);
    sb = cadd(sb, pp[tid + 256]);
    if (tid == 0) s5 = cadd(s5, pp[512]);
  }
  // full Hermitian spectrum: S[w] for w<=512 from sums, S[1024-w]=conj(S[w])
  S[tid] = sa;
  S[tid + 256] = sb;
  if (tid == 0) S[512] = s5;
  if (tid > 0) S[1024 - tid] = c32{sa.x, -sa.y};  // 769..1023
  S[768 - tid] = c32{sb.x, -sb.y};                // 513..768
  __syncthreads();
#pragma unroll
  for (int k = 0; k < 4; ++k) {
    int t = tid + k * 256;
    zz[ZIDX(drev4(t))] = S[t];
  }
  __syncthreads();
  for (int s = 0; s < 5; ++s) {
    fft_stage<1>(&zz[0], twl, tid, s);
    __syncthreads();
  }
  const float scl = 1.0f / (1024.0f * 512.0f);  // irfft 1/N * mean over 512 dims
#pragma unroll
  for (int k = 0; k < 4; ++k) {
    int t = tid + k * 256;
    corr[t] = zz[ZIDX(t)].x * scl;
  }
  __syncthreads();
  // top-20 (smallest-index tie-break, matches jax.lax.top_k stability)
  __shared__ float swv[4];
  __shared__ int swi[4];
  __shared__ float selv[CTOPK];
  __shared__ int seli[CTOPK];
  int wid = tid >> 6, lane = tid & 63;
  for (int k = 0; k < CTOPK; ++k) {
    float bv = -INFINITY;
    int bi = 0;
#pragma unroll
    for (int q = 0; q < 4; ++q) {
      int idx = tid + q * 256;
      float v = corr[idx];
      if (v > bv || (v == bv && idx < bi)) { bv = v; bi = idx; }
    }
#pragma unroll
    for (int off = 32; off > 0; off >>= 1) {
      float ov = __shfl_down(bv, off);
      int oi = __shfl_down(bi, off);
      if (ov > bv || (ov == bv && oi < bi)) { bv = ov; bi = oi; }
    }
    if (lane == 0) { swv[wid] = bv; swi[wid] = bi; }
    __syncthreads();
    if (tid == 0) {
      float mvv = swv[0];
      int mi = swi[0];
      for (int q2 = 1; q2 < 4; ++q2)
        if (swv[q2] > mvv || (swv[q2] == mvv && swi[q2] < mi)) { mvv = swv[q2]; mi = swi[q2]; }
      selv[k] = mvv;
      seli[k] = mi;
      corr[mi] = -INFINITY;
    }
    __syncthreads();
  }
  if (tid == 0) {
    float mx = selv[0], sum = 0.f, e[CTOPK];
    for (int k = 0; k < CTOPK; ++k) {
      e[k] = expf(selv[k] - mx);
      sum += e[k];
    }
    float inv = 1.0f / sum;
    for (int k = 0; k < CTOPK; ++k) {
      wts[b * CTOPK + k] = e[k] * inv;
      idxs[b * CTOPK + k] = seli[k];
    }
  }
}

// ---------------- delay aggregation: bf16 V [Mc][512]; XCD-swizzled -----------------
// (bf16-V numeric chain verified passing in R0/R1/R4 at absmax 1.9-2.3e-5)
__global__ __launch_bounds__(128) void k_agg(const ushort* __restrict__ Vf,
                                             const float* __restrict__ wts,
                                             const int* __restrict__ idxs,
                                             ushort* __restrict__ out2) {
  int nb = gridDim.x;
  int blk = blockIdx.x;
  int row = (blk & 7) * (nb >> 3) + (blk >> 3);
  int b = row >> 10, t = row & 1023;
  int d0 = threadIdx.x * 4;
  const ushort* Vb = Vf + (size_t)b * CT * 512;
  float4 acc = {0.f, 0.f, 0.f, 0.f};
#pragma unroll
  for (int k = 0; k < CTOPK; ++k) {
    float w = wts[b * CTOPK + k];
    int r = t + idxs[b * CTOPK + k];
    if (r >= CT) r -= CT;
    ushort4 v = *(const ushort4*)(Vb + (size_t)r * 512 + d0);
    acc.x += w * bf16f(v.x);
    acc.y += w * bf16f(v.y);
    acc.z += w * bf16f(v.z);
    acc.w += w * bf16f(v.w);
  }
  ushort4 hv = {bf16r(acc.x), bf16r(acc.y), bf16r(acc.z), bf16r(acc.w)};
  *(ushort4*)(out2 + (size_t)row * CD + d0) = hv;
}

// ---------------- fused LN + series decomp, SLIDING WINDOW --------------------------
// seasonal[t,d] = g_d * ( z(t,d) - (1/25) sum_{j=-12..12} z(clamp(t+j),d) ),
// z(u,d) = (X[u,d]-mu_u)*rs_u.  Running sum: s(t+1) = s(t) + z(min(t+13,T-1))
// - z(max(t-12,0)) -> each element read ~3x instead of 25x.
// Block: 256 threads = cols {tid, tid+256}; t-chunk of 64; grid (T/64, Bc).
__global__ __launch_bounds__(256) void k_dec2(const float* __restrict__ X,
                                              const c32* __restrict__ st,
                                              const float* __restrict__ g,
                                              float* __restrict__ out,
                                              ushort* __restrict__ out2) {
  int b = blockIdx.y;
  int t0 = blockIdx.x * 64;
  int tid = threadIdx.x;
  const float* xb = X + (size_t)b * CT * CD;
  const c32* sb = st + (size_t)b * CT;
  float g0v = g[tid], g1v = g[tid + 256];
  float s0 = 0.f, s1 = 0.f;
#pragma unroll
  for (int j = -12; j <= 12; ++j) {
    int u = t0 + j;
    u = u < 0 ? 0 : (u > CT - 1 ? CT - 1 : u);
    c32 ms = sb[u];
    s0 += (xb[(size_t)u * CD + tid] - ms.x) * ms.y;
    s1 += (xb[(size_t)u * CD + tid + 256] - ms.x) * ms.y;
  }
  const float inv = 1.0f / 25.0f;
  for (int tt = 0; tt < 64; ++tt) {
    int t = t0 + tt;
    c32 mc = sb[t];
    float z0 = (xb[(size_t)t * CD + tid] - mc.x) * mc.y;
    float z1 = (xb[(size_t)t * CD + tid + 256] - mc.x) * mc.y;
    float o0 = g0v * (z0 - s0 * inv);
    float o1 = g1v * (z1 - s1 * inv);
    size_t ro = (size_t)(b * CT + t) * CD;
    out[ro + tid] = o0;
    out[ro + tid + 256] = o1;
    out2[ro + tid] = bf16r(o0);
    out2[ro + tid + 256] = bf16r(o1);
    // slide window t -> t+1: add z(min(t+13)), remove z(max(t-12))
    int ua = t + 13;
    ua = ua > CT - 1 ? CT - 1 : ua;
    int ur = t - 12;
    ur = ur < 0 ? 0 : ur;
    c32 ma = sb[ua], mr = sb[ur];
    s0 += (xb[(size_t)ua * CD + tid] - ma.x) * ma.y -
          (xb[(size_t)ur * CD + tid] - mr.x) * mr.y;
    s1 += (xb[(size_t)ua * CD + tid + 256] - ma.x) * ma.y -
          (xb[(size_t)ur * CD + tid + 256] - mr.x) * mr.y;
  }
}

// ---------------- partial time-mean: grid (Bc, 8), coalesced ------------------------
__global__ __launch_bounds__(256) void k_meanp(const float* __restrict__ X,
                                               float* __restrict__ part) {
  int b = blockIdx.x, g = blockIdx.y, tid = threadIdx.x;
  const float* xb = X + (size_t)b * CT * CD + (size_t)g * 128 * CD;
  float a0 = 0.f, a1 = 0.f;
  for (int r = 0; r < 128; ++r) {
    a0 += xb[(size_t)r * CD + tid];
    a1 += xb[(size_t)r * CD + tid + 256];
  }
  part[((size_t)b * 8 + g) * CD + tid] = a0;
  part[((size_t)b * 8 + g) * CD + tid + 256] = a1;
}

// ---------------- final head: mean-combine + 2-layer MLP ----------------------------
__global__ __launch_bounds__(256) void k_headf(const float* __restrict__ part,
                                               const float* __restrict__ w1,
                                               const float* __restrict__ b1,
                                               const float* __restrict__ w2,
                                               const float* __restrict__ b2,
                                               float* __restrict__ out) {
  int b = blockIdx.x, tid = threadIdx.x;
  __shared__ float f[CD];
  __shared__ float hid[CFCH];
  for (int d = tid; d < CD; d += 256) {
    float s = 0.f;
#pragma unroll
    for (int g = 0; g < 8; ++g) s += part[((size_t)b * 8 + g) * CD + d];
    f[d] = s * (1.0f / CT);
  }
  __syncthreads();
  float a = b1[tid];
  for (int d = 0; d < CD; ++d) a += f[d] * w1[d * CFCH + tid];
  hid[tid] = fmaxf(a, 0.f);
  __syncthreads();
  if (tid < CNC) {
    float a2 = b2[tid];
    for (int j = 0; j < CFCH; ++j) a2 += hid[j] * w2[j * CNC + tid];
    out[b * CNC + tid] = a2;
  }
}

// =====================================================================================
extern "C" void kernel_launch(void* const* d_in, const int* in_sizes, int n_in,
                              void* d_out, int out_size, void* d_ws, size_t ws_size,
                              hipStream_t stream) {
  const float* x = (const float*)d_in[0];
  const float* emb_w = (const float*)d_in[1];
  const float* emb_g = (const float*)d_in[2];
  const float* emb_b = (const float*)d_in[3];
  const float* attn_w = (const float*)d_in[4];
  const float* attn_b = (const float*)d_in[5];
  const float* ln_g = (const float*)d_in[6];
  const float* ln_bb = (const float*)d_in[7];
  const float* fc1_w = (const float*)d_in[8];
  const float* fc1_b = (const float*)d_in[9];
  const float* fc2_w = (const float*)d_in[10];
  const float* fc2_b = (const float*)d_in[11];
  const float* hw1 = (const float*)d_in[12];
  const float* hb1 = (const float*)d_in[13];
  const float* hw2 = (const float*)d_in[14];
  const float* hb2 = (const float*)d_in[15];
  float* outp = (float*)d_out;

  // per-layer bf16 weights (ushorts): wq,wk,wv (contig => fused QKV), wo, w1, w2
  const size_t WQ = 262144ULL;                         // 512*512
  const size_t LW = 4 * WQ + 1048576ULL + 1048576ULL;  // 3,145,728 ushorts
  const size_t W2TOT = CL * LW;

  const size_t FIXED_B = W2TOT * 2                     // bf16 weights
                         + (size_t)CT * CD * 4         // postab
                         + 2 * (size_t)CB * CCH * 4    // sc,lg
                         + 2 * (size_t)CB * CTOPK * 4  // wts,idxs
                         + (size_t)CB * 8 * CD * 4     // mean partials
                         + 1024 * 8                    // twiddles
                         + 4096;
  // per-b bytes: HP(2MB) + SA(2MB, doubles as bf16 V [T][512]) + U0(1MB)
  //              + U1 (qkv: fp32 QT [1024][Mc] / ffn: bf16 f2 [T][2048]) (4MB)
  //              + FFT partials + LN stats + st8 partials
  const size_t PERB = 2ULL * CT * CD * 4 + (size_t)CT * CD * 2 + (size_t)CT * 2048 * 2 +
                      (size_t)32 * 513 * 8 + (size_t)CT * 8 + (size_t)CT * 64;
  int Bc = CB;
  while (Bc > 1) {
    if ((size_t)Bc * PERB + FIXED_B <= ws_size) break;
    Bc >>= 1;
  }
  const size_t CHF = (size_t)Bc * CT * CD;

  char* wsp = (char*)d_ws;
  float* P0 = (float*)wsp;     wsp += CHF * 4;
  float* P1 = (float*)wsp;     wsp += CHF * 4;
  ushort* U0 = (ushort*)wsp;   wsp += CHF * 2;            // h2 / agg-out / d2
  ushort* U1 = (ushort*)wsp;   wsp += (size_t)Bc * CT * 2048 * 2;  // fp32 QT / bf16 f2
  ushort* W2b = (ushort*)wsp;  wsp += W2TOT * 2;
  float* postab = (float*)wsp; wsp += (size_t)CT * CD * 4;
  float* scb = (float*)wsp;    wsp += (size_t)CB * CCH * 4;
  float* lgb = (float*)wsp;    wsp += (size_t)CB * CCH * 4;
  float* wtb = (float*)wsp;    wsp += (size_t)CB * CTOPK * 4;
  int* idb = (int*)wsp;        wsp += (size_t)CB * CTOPK * 4;
  float* partb = (float*)wsp;  wsp += (size_t)CB * 8 * CD * 4;
  c32* twc = (c32*)wsp;        wsp += 1024 * sizeof(c32);
  c32* partc = (c32*)wsp;      wsp += (size_t)Bc * 32 * 513 * sizeof(c32);
  c32* stb = (c32*)wsp;        wsp += (size_t)Bc * CT * sizeof(c32);
  c32* st8b = (c32*)wsp;       wsp += (size_t)Bc * CT * 8 * sizeof(c32);

  // ---- convert all weights to transposed bf16 [N][K], once per call ----
  for (int l = 0; l < CL; ++l) {
    ushort* wq2 = W2b + l * LW;      // [1536][512] fused QKV (q,k,v contiguous)
    ushort* w12 = wq2 + 4 * WQ;
    ushort* w22 = w12 + 1048576;
    // 4 attn matrices (q,k,v,o) batched via blockIdx.z
    k_cvtw<<<dim3(CD / 32, CD / 32, 4), 256, 0, stream>>>(
        attn_w + (size_t)l * 4 * CD * CD, wq2, CD, CD);
    k_cvtw<<<dim3(CFFN / 32, CD / 32, 1), 256, 0, stream>>>(
        fc1_w + (size_t)l * CD * CFFN, w12, CD, CFFN);
    k_cvtw<<<dim3(CD / 32, CFFN / 32, 1), 256, 0, stream>>>(
        fc2_w + (size_t)l * CFFN * CD, w22, CFFN, CD);
  }

  k_scale<<<CB, 256, 0, stream>>>(x, scb, lgb);
  k_postab<<<CT, 512, 0, stream>>>(postab);
  k_twid<<<4, 256, 0, stream>>>(twc);

  for (int b0 = 0; b0 < CB; b0 += Bc) {
    const int Mc = Bc * CT;

    float* HP = P0;  // h fp32 (stable across layers; no swap needed)
    float* SA = P1;  // scratch: bf16 V / attn-out / ffn-out

    k_embed<<<Mc, 128, 0, stream>>>(x + (size_t)b0 * CT * CCH, scb + b0 * CCH,
                                    lgb + b0 * CCH, emb_w, postab, emb_g, emb_b,
                                    HP, U0);

    for (int l = 0; l < CL; ++l) {
      const float* bqkv = attn_b + (size_t)l * 4 * CD;  // q,k,v biases contiguous
      const float* bo = attn_b + (size_t)(l * 4 + 3) * CD;
      const float* g0 = ln_g + (size_t)(l * 2 + 0) * CD;
      const float* g1 = ln_g + (size_t)(l * 2 + 1) * CD;
      const float* B1 = fc1_b + (size_t)l * CFFN;
      const float* B2f = fc2_b + (size_t)l * CD;
      const ushort* wq2 = W2b + l * LW;
      const ushort* wo2 = wq2 + 3 * WQ;
      const ushort* w12 = wq2 + 4 * WQ;
      const ushort* w22 = w12 + 1048576;

      // fused QKV projection: fp32 Q,K TRANSPOSED -> U1 QT[1024][Mc]; bf16 V -> SA
      k_gemm3<7><<<dim3(1536 / 128, Mc / 128), 256, 0, stream>>>(
          U0, wq2, bqkv, nullptr, (float*)U1, (ushort*)SA, nullptr, CD, CD, Mc, CD);
      // packed-real FFT autocorrelation: product spectra -> partc
      k_fft<<<dim3(32, Bc), 256, 0, stream>>>((const float*)U1, twc, partc, Mc);
      // spectrum reduce + irfft + top-20 + softmax
      k_spectopk<<<Bc, 256, 0, stream>>>(partc, twc, wtb, idb);
      // delay aggregation (bf16 V in SA) -> U0 bf16
      k_agg<<<Mc, 128, 0, stream>>>((const ushort*)SA, wtb, idb, U0);
      // O proj (+residual HP) -> SA, with fused LN-stats partials
      k_gemm3<3><<<dim3(CD / 128, Mc / 128), 256, 0, stream>>>(
          U0, wo2, bo, HP, (float*)SA, nullptr, (ushort*)st8b, CD, CD, CD, CD);
      k_finst<<<Mc / 256, 256, 0, stream>>>(st8b, stb);
      k_dec2<<<dim3(CT / 64, Bc), 256, 0, stream>>>((float*)SA, stb, g0, HP, U0);
      // FFN: FC1 (GELU -> bf16 f2 = U1 [Mc][2048]), FC2 (+res HP, stats) -> SA
      k_gemm3<1><<<dim3(CFFN / 128, Mc / 128), 256, 0, stream>>>(
          U0, w12, B1, nullptr, nullptr, U1, nullptr, CD, CD, CFFN, CD);
      k_gemm3<3><<<dim3(CD / 128, Mc / 128), 256, 0, stream>>>(
          U1, w22, B2f, HP, (float*)SA, nullptr, (ushort*)st8b, CFFN, CFFN, CD, CFFN);
      k_finst<<<Mc / 256, 256, 0, stream>>>(st8b, stb);
      k_dec2<<<dim3(CT / 64, Bc), 256, 0, stream>>>((float*)SA, stb, g1, HP, U0);
    }

    k_meanp<<<dim3(Bc, 8), 256, 0, stream>>>(HP, partb + (size_t)b0 * 8 * CD);
    k_headf<<<Bc, 256, 0, stream>>>(partb + (size_t)b0 * 8 * CD, hw1, hb1, hw2, hb2,
                                    outp + (size_t)b0 * CNC);
  }
}

// Round 8
// 2781.987 us; speedup vs baseline: 1.0295x; 1.0295x over previous
//
#include <hip/hip_runtime.h>
#include <math.h>

#define CB 64      // batch
#define CT 1024    // time
#define CCH 12     // channels
#define CD 512     // d_model
#define CL 2       // layers
#define CFFN 2048
#define CFCH 256
#define CNC 5
#define CTOPK 20
#define CEPS 1e-5f

typedef __attribute__((ext_vector_type(8))) short bfrag;
typedef __attribute__((ext_vector_type(4))) float ffrag;

__device__ inline ushort bf16r(float f) {
  unsigned u = __float_as_uint(f);
  unsigned r = (u + 0x7FFFu + ((u >> 16) & 1u)) >> 16;
  return (ushort)r;
}
__device__ inline float bf16f(ushort h) { return __uint_as_float(((unsigned)h) << 16); }

// async 16B global->LDS (lds dest = wave-uniform base + lane*16)
__device__ __forceinline__ void gld16(const ushort* g, ushort* l) {
  __builtin_amdgcn_global_load_lds((__attribute__((address_space(1))) void*)g,
                                   (__attribute__((address_space(3))) void*)l,
                                   16, 0, 0);
}

// ---------------- complex helpers ----------------
struct c32 { float x, y; };
__device__ inline c32 cadd(c32 a, c32 b) { return c32{a.x + b.x, a.y + b.y}; }
__device__ inline c32 csub(c32 a, c32 b) { return c32{a.x - b.x, a.y - b.y}; }
__device__ inline c32 cmul(c32 a, c32 b) {  // a*b
  return c32{a.x * b.x - a.y * b.y, a.x * b.y + a.y * b.x};
}
__device__ inline c32 cmulj(c32 a, c32 b) {  // a*conj(b)
  return c32{a.x * b.x + a.y * b.y, a.y * b.x - a.x * b.y};
}
__device__ inline c32 mineg_i(c32 a) { return c32{a.y, -a.x}; }  // -i*a
__device__ inline c32 mul_i(c32 a) { return c32{-a.y, a.x}; }    // +i*a

// LDS padding: +1 c32 per 16 -> balanced 4-way (wave64 minimum) on every
// stage stride and on the digit-reversed scatter.
#define ZIDX(p) ((p) + ((p) >> 4))

// base-4 digit reversal of 5 digits (N=1024=4^5); involution
__device__ inline int drev4(int t) {
  return ((t & 3) << 8) | (((t >> 2) & 3) << 6) | (((t >> 4) & 3) << 4) |
         (((t >> 6) & 3) << 2) | ((t >> 8) & 3);
}

// radix-4 DIT stage s (in-place; input digit-reversed, output natural).
template <int INV>
__device__ inline void fft_stage(c32* zz, const c32* twl, int tid, int s) {
  int L = 1 << (2 * s);
  int j = tid & (L - 1);
  int g = tid >> (2 * s);
  int p0 = (g << (2 * s + 2)) + j;
  int tb = j << (8 - 2 * s);
  c32 w1 = twl[ZIDX(tb)], w2 = twl[ZIDX(2 * tb)], w3 = twl[ZIDX(3 * tb)];
  c32 b0 = zz[ZIDX(p0)], b1 = zz[ZIDX(p0 + L)], b2 = zz[ZIDX(p0 + 2 * L)],
      b3 = zz[ZIDX(p0 + 3 * L)];
  if (INV) { b1 = cmulj(b1, w1); b2 = cmulj(b2, w2); b3 = cmulj(b3, w3); }
  else     { b1 = cmul(b1, w1);  b2 = cmul(b2, w2);  b3 = cmul(b3, w3); }
  c32 e0 = cadd(b0, b2), e1 = csub(b0, b2), e2 = cadd(b1, b3), e3 = csub(b1, b3);
  c32 e3r = INV ? mul_i(e3) : mineg_i(e3);
  zz[ZIDX(p0)] = cadd(e0, e2);
  zz[ZIDX(p0 + L)] = cadd(e1, e3r);
  zz[ZIDX(p0 + 2 * L)] = csub(e0, e2);
  zz[ZIDX(p0 + 3 * L)] = csub(e1, e3r);
}

// unpack packed-real FFT (z=q+ik, ZIDX-padded) at bin w; accumulate P = Qf*conj(Kf)
__device__ inline void unp_acc(const c32* zf, int w, c32& acc) {
  int wc = (1024 - w) & 1023;
  c32 Z1 = zf[ZIDX(w)];
  c32 Z2r = zf[ZIDX(wc)];
  c32 Z2 = c32{Z2r.x, -Z2r.y};                       // conj(Z[N-w])
  c32 Qf = c32{0.5f * (Z1.x + Z2.x), 0.5f * (Z1.y + Z2.y)};
  c32 M = c32{Z1.x - Z2.x, Z1.y - Z2.y};
  c32 Kf = c32{0.5f * M.y, -0.5f * M.x};             // -0.5i*M
  acc.x += Qf.x * Kf.x + Qf.y * Kf.y;                // Qf*conj(Kf)
  acc.y += Qf.y * Kf.x - Qf.x * Kf.y;
}

// ---------------- twiddle table, fp64-accurate (one-time) ---------------------------
__global__ __launch_bounds__(256) void k_twid(c32* __restrict__ tw) {
  int j = blockIdx.x * 256 + threadIdx.x;  // 0..1023
  double a = -2.0 * 3.14159265358979323846 * (double)j / 1024.0;
  tw[j] = c32{(float)cos(a), (float)sin(a)};
}

// ---------------- mean-abs scaler ----------------
__global__ __launch_bounds__(256) void k_scale(const float* __restrict__ x,
                                               float* __restrict__ sc,
                                               float* __restrict__ lg) {
  int b = blockIdx.x, tid = threadIdx.x;
  float acc[CCH];
#pragma unroll
  for (int c = 0; c < CCH; ++c) acc[c] = 0.f;
  const float* xb = x + (size_t)b * CT * CCH;
  for (int t = tid; t < CT; t += 256) {
    const float* row = xb + t * CCH;
#pragma unroll
    for (int c = 0; c < CCH; ++c) acc[c] += fabsf(row[c]);
  }
  __shared__ float red[256][CCH];
#pragma unroll
  for (int c = 0; c < CCH; ++c) red[tid][c] = acc[c];
  __syncthreads();
  for (int off = 128; off > 0; off >>= 1) {
    if (tid < off) {
#pragma unroll
      for (int c = 0; c < CCH; ++c) red[tid][c] += red[tid + off][c];
    }
    __syncthreads();
  }
  if (tid < CCH) {
    float s = fmaxf(red[0][tid] * (1.0f / CT), 1e-10f);
    sc[b * CCH + tid] = s;
    lg[b * CCH + tid] = logf(s);
  }
}

// ---------------- sinusoidal position table (f64, matches np) ----------------
__global__ __launch_bounds__(512) void k_postab(float* __restrict__ pos) {
  int t = blockIdx.x;
  int d = threadIdx.x;
  double v;
  if (d < 256) {
    double w = pow(10000.0, -((double)d) / 256.0);
    v = sin((double)t * w);
  } else {
    double w = pow(10000.0, -((double)(d - 256)) / 256.0);
    v = cos((double)t * w);
  }
  pos[(size_t)t * CD + d] = (float)v;
}

// ---------------- embedding + LN fused; writes fp32 h AND bf16 h2 -------------------
__global__ __launch_bounds__(128) void k_embed(const float* __restrict__ x,
                                               const float* __restrict__ sc,
                                               const float* __restrict__ lg,
                                               const float* __restrict__ W,
                                               const float* __restrict__ postab,
                                               const float* __restrict__ g,
                                               const float* __restrict__ beta,
                                               float* __restrict__ h,
                                               ushort* __restrict__ h2) {
  int row = blockIdx.x;  // local: b*T + t
  int b = row >> 10, t = row & 1023;
  int tid = threadIdx.x;
  __shared__ float xs[CCH], ls[CCH];
  if (tid < CCH) {
    float s = sc[b * CCH + tid];
    xs[tid] = x[(size_t)row * CCH + tid] / s;
    ls[tid] = lg[b * CCH + tid];
  }
  __syncthreads();
  int d0 = tid * 4;
  float4 p = *(const float4*)(postab + (size_t)t * CD + d0);
  float v0 = p.x, v1 = p.y, v2 = p.z, v3 = p.w;
#pragma unroll
  for (int c = 0; c < CCH; ++c) {
    float xc = xs[c], lc = ls[c];
    float4 w0 = *(const float4*)(W + (size_t)c * CD + d0);
    float4 w1 = *(const float4*)(W + (size_t)(24 + c) * CD + d0);
    v0 += xc * w0.x + lc * w1.x;
    v1 += xc * w0.y + lc * w1.y;
    v2 += xc * w0.z + lc * w1.z;
    v3 += xc * w0.w + lc * w1.w;
  }
  float s1 = v0 + v1 + v2 + v3;
  float s2 = v0 * v0 + v1 * v1 + v2 * v2 + v3 * v3;
  for (int off = 32; off > 0; off >>= 1) {
    s1 += __shfl_down(s1, off);
    s2 += __shfl_down(s2, off);
  }
  __shared__ float ws1[2], ws2[2], mv[2];
  int wid = tid >> 6, lane = tid & 63;
  if (lane == 0) { ws1[wid] = s1; ws2[wid] = s2; }
  __syncthreads();
  if (tid == 0) {
    float S1 = ws1[0] + ws1[1], S2 = ws2[0] + ws2[1];
    float mu = S1 * (1.0f / CD);
    float var = S2 * (1.0f / CD) - mu * mu;
    mv[0] = mu;
    mv[1] = 1.0f / sqrtf(var + CEPS);
  }
  __syncthreads();
  float mu = mv[0], ri = mv[1];
  float4 gg = *(const float4*)(g + d0);
  float4 bb = *(const float4*)(beta + d0);
  float4 o;
  o.x = (v0 - mu) * ri * gg.x + bb.x;
  o.y = (v1 - mu) * ri * gg.y + bb.y;
  o.z = (v2 - mu) * ri * gg.z + bb.z;
  o.w = (v3 - mu) * ri * gg.w + bb.w;
  *(float4*)(h + (size_t)row * CD + d0) = o;
  ushort4 hv = {bf16r(o.x), bf16r(o.y), bf16r(o.z), bf16r(o.w)};
  *(ushort4*)(h2 + (size_t)row * CD + d0) = hv;
}

// ---------------- weight convert+transpose: W[K][N] fp32 -> W2[N][K] bf16 -----------
// blockIdx.z batches multiple same-shape matrices (stride K*N on both sides).
__global__ __launch_bounds__(256) void k_cvtw(const float* __restrict__ W,
                                              ushort* __restrict__ W2,
                                              int K, int N) {
  __shared__ float tile[32][33];
  size_t zoff = (size_t)blockIdx.z * K * N;
  int tx = threadIdx.x & 31, ty = threadIdx.x >> 5;  // ty 0..7
  int n0 = blockIdx.x * 32, k0 = blockIdx.y * 32;
#pragma unroll
  for (int r = 0; r < 4; ++r)
    tile[ty * 4 + r][tx] = W[zoff + (size_t)(k0 + ty * 4 + r) * N + n0 + tx];
  __syncthreads();
#pragma unroll
  for (int r = 0; r < 4; ++r) {
    int nl = ty * 4 + r, kl = tx;
    W2[zoff + (size_t)(n0 + nl) * K + k0 + kl] = bf16r(tile[kl][nl]);
  }
}

// ---------------- bf16 MFMA GEMM, 128x128 tile, BK=32, double-buffered pipeline -----
// A: [M][lda] bf16 k-contig rows; W: [N][ldb] bf16 k-contig rows.
// LDS chunk swizzle: chunk q of row r at slot q^((r>>2)&3) -> 2-way bank access (free).
// Pipeline: prefetch distance 2; per-iter wait `s_waitcnt vmcnt(4)`.
// Launch bounds: PLAIN 256 (R5 A/B: forcing 4 waves/SIMD raised occupancy 27->38%
// with zero speedup -> occupancy is not the limiter; the cap cost ~100us elsewhere).
// NOTE: a 128x256 variant (k_gemm4) hung the container twice (R6/R7) -> parked.
// Grid: XCD-chunked bijective swizzle of the flat block id (nwg always %8==0 here).
// EPI: 0=bias->fp32  1=bias+GELU->bf16  2=bias+residual->fp32
//      3=bias+residual->fp32 + per-row LN-stats partials (Cs2 = st8[M][8] c32)
//      7=QKV: cols<1024 -> TRANSPOSED fp32 Cf[col][ldc], cols>=1024 -> V bf16
template <int EPI>
__global__ __launch_bounds__(256) void k_gemm3(const ushort* __restrict__ A,
                                               const ushort* __restrict__ W,
                                               const float* __restrict__ bias,
                                               const float* __restrict__ R,
                                               float* __restrict__ Cf,
                                               ushort* __restrict__ Cs,
                                               ushort* __restrict__ Cs2,
                                               int lda, int ldb, int ldc, int K) {
  __shared__ ushort AhS[2][128 * 32];
  __shared__ ushort BhS[2][128 * 32];
  int tid = threadIdx.x;
  int nx = gridDim.x;
  int nwg = nx * gridDim.y;
  int flat = blockIdx.y * nx + blockIdx.x;
  int sw = (flat & 7) * (nwg >> 3) + (flat >> 3);
  int n0 = (sw % nx) * 128, m0 = (sw / nx) * 128;
  int wid = __builtin_amdgcn_readfirstlane(tid >> 6);
  int lane = tid & 63;
  int lr = lane >> 2;                              // 0..15: row in a 16-row gld16 group
  int lc = ((lane & 3) ^ ((lr >> 2) & 3)) * 8;     // swizzled source chunk (ushorts)
  int wm = wid >> 1, wn = wid & 1;
  int mOff = wm * 64, nOff = wn * 64;
  int quad = lane >> 4, l16 = lane & 15;

  const ushort* pA = A + (size_t)(m0 + wid * 32 + lr) * lda + lc;
  const ushort* pB = W + (size_t)(n0 + wid * 32 + lr) * ldb + lc;
  const int NK = K >> 5;

  ffrag acc[4][4];
#pragma unroll
  for (int i = 0; i < 4; ++i)
#pragma unroll
    for (int j = 0; j < 4; ++j) acc[i][j] = (ffrag)(0.f);

#define ISSUE(t, buf)                                                        \
  {                                                                          \
    int kk = (t) << 5;                                                       \
    ushort* lA = &AhS[buf][(wid * 32) * 32];                                 \
    ushort* lB = &BhS[buf][(wid * 32) * 32];                                 \
    gld16(pA + kk, lA);                                                      \
    gld16(pA + (size_t)16 * lda + kk, lA + 16 * 32);                         \
    gld16(pB + kk, lB);                                                      \
    gld16(pB + (size_t)16 * ldb + kk, lB + 16 * 32);                         \
  }

  ISSUE(0, 0);
  ISSUE(1, 1);
  for (int k = 0; k < NK; ++k) {
    if (k + 1 < NK) {
      asm volatile("s_waitcnt vmcnt(4)\n\ts_barrier" ::: "memory");
    } else {
      asm volatile("s_waitcnt vmcnt(0)\n\ts_barrier" ::: "memory");
    }
    int buf = k & 1;
    bfrag ah[4], bh[4];
#pragma unroll
    for (int i = 0; i < 4; ++i) {
      int row = mOff + i * 16 + l16;
      ah[i] = *(const bfrag*)&AhS[buf][row * 32 + (quad ^ ((row >> 2) & 3)) * 8];
    }
#pragma unroll
    for (int j = 0; j < 4; ++j) {
      int row = nOff + j * 16 + l16;
      bh[j] = *(const bfrag*)&BhS[buf][row * 32 + (quad ^ ((row >> 2) & 3)) * 8];
    }
#pragma unroll
    for (int i = 0; i < 4; ++i)
#pragma unroll
      for (int j = 0; j < 4; ++j)
        acc[i][j] = __builtin_amdgcn_mfma_f32_16x16x32_bf16(ah[i], bh[j], acc[i][j], 0, 0, 0);
    asm volatile("s_barrier" ::: "memory");
    if (k + 2 < NK) ISSUE(k + 2, buf);
  }
#undef ISSUE

  // C tile layout: col = lane&15, row = quad*4 + reg (verified R3-R10)
  if (EPI == 3) {
    c32* st8 = (c32*)Cs2;
#pragma unroll
    for (int i = 0; i < 4; ++i) {
#pragma unroll
      for (int r = 0; r < 4; ++r) {
        int row = m0 + mOff + i * 16 + quad * 4 + r;
        float s1 = 0.f, s2 = 0.f;
#pragma unroll
        for (int j = 0; j < 4; ++j) {
          int col = n0 + nOff + j * 16 + l16;
          float vv = acc[i][j][r] + bias[col] + R[(size_t)row * ldc + col];
          Cf[(size_t)row * ldc + col] = vv;
          s1 += vv;
          s2 += vv * vv;
        }
#pragma unroll
        for (int off = 8; off > 0; off >>= 1) {
          s1 += __shfl_xor(s1, off);
          s2 += __shfl_xor(s2, off);
        }
        if (l16 == 0) st8[(size_t)row * 8 + (n0 >> 6) + wn] = c32{s1, s2};
      }
    }
  } else {
#pragma unroll
    for (int j = 0; j < 4; ++j) {
      int col = n0 + nOff + j * 16 + l16;
      float bcol = bias[col];
#pragma unroll
      for (int i = 0; i < 4; ++i) {
        int rowb = m0 + mOff + i * 16 + quad * 4;
        if (EPI == 7) {
          if (col < 1024) {
            float4 o = {acc[i][j][0] + bcol, acc[i][j][1] + bcol,
                        acc[i][j][2] + bcol, acc[i][j][3] + bcol};
            *(float4*)(Cf + (size_t)col * ldc + rowb) = o;
          } else {
#pragma unroll
            for (int r = 0; r < 4; ++r)
              Cs[(size_t)(rowb + r) * 512 + (col - 1024)] = bf16r(acc[i][j][r] + bcol);
          }
        } else {
#pragma unroll
          for (int r = 0; r < 4; ++r) {
            int row = rowb + r;
            float vv = acc[i][j][r] + bcol;
            if (EPI == 1) vv = 0.5f * vv * (1.0f + erff(vv * 0.7071067811865475f));
            if (EPI == 2) vv += R[(size_t)row * ldc + col];
            if (EPI == 1) {
              Cs[(size_t)row * ldc + col] = bf16r(vv);
            } else {
              Cf[(size_t)row * ldc + col] = vv;
            }
          }
        }
      }
    }
  }
}

// ---------------- combine st8 partials -> (mu, 1/sigma) per row ---------------------
__global__ __launch_bounds__(256) void k_finst(const c32* __restrict__ st8,
                                               c32* __restrict__ st) {
  int row = blockIdx.x * 256 + threadIdx.x;
  float s1 = 0.f, s2 = 0.f;
#pragma unroll
  for (int p = 0; p < 8; ++p) {
    c32 v = st8[(size_t)row * 8 + p];
    s1 += v.x;
    s2 += v.y;
  }
  float mu = s1 * (1.0f / CD);
  float var = s2 * (1.0f / CD) - mu * mu;
  st[row] = c32{mu, 1.0f / sqrtf(var + CEPS)};
}

// ---------------- autocorrelation via packed-real FFT (transposed input) ------------
__global__ __launch_bounds__(256) void k_fft(const float* __restrict__ QT,
                                             const c32* __restrict__ twg,
                                             c32* __restrict__ part, int Mc) {
  __shared__ c32 z[4][1088];
  __shared__ c32 twl[1088];
  int dg = blockIdx.x, zb = blockIdx.y, tid = threadIdx.x;
#pragma unroll
  for (int k = 0; k < 4; ++k) {
    int i = tid + k * 256;
    twl[ZIDX(i)] = twg[i];
  }
  c32 pa = {0.f, 0.f}, pb = {0.f, 0.f}, p5 = {0.f, 0.f};
  for (int i = 0; i < 4; ++i) {
    int d0 = dg * 16 + i * 4;
#pragma unroll
    for (int f = 0; f < 4; ++f) {
      const float* qr = QT + (size_t)(d0 + f) * Mc + (size_t)zb * 1024;
      const float* kr = QT + (size_t)(512 + d0 + f) * Mc + (size_t)zb * 1024;
#pragma unroll
      for (int k = 0; k < 4; ++k) {
        int t = tid + k * 256;
        z[f][ZIDX(drev4(t))] = c32{qr[t], kr[t]};
      }
    }
    __syncthreads();  // also covers twl on first iter
    for (int s = 0; s < 5; ++s) {
#pragma unroll
      for (int f = 0; f < 4; ++f) fft_stage<0>(&z[f][0], twl, tid, s);
      __syncthreads();
    }
#pragma unroll
    for (int f = 0; f < 4; ++f) {
      unp_acc(&z[f][0], tid, pa);
      unp_acc(&z[f][0], tid + 256, pb);
      if (tid == 0) unp_acc(&z[f][0], 512, p5);
    }
    __syncthreads();  // before next iter overwrites z
  }
  c32* po = part + ((size_t)zb * 32 + dg) * 513;
  po[tid] = pa;
  po[tid + 256] = pb;
  if (tid == 0) po[512] = p5;
}

// ---------------- spectrum reduce + irfft + top-20 + softmax (fused) ----------------
__global__ __launch_bounds__(256) void k_spectopk(const c32* __restrict__ part,
                                                  const c32* __restrict__ twg,
                                                  float* __restrict__ wts,
                                                  int* __restrict__ idxs) {
  int b = blockIdx.x, tid = threadIdx.x;
  __shared__ c32 twl[1088];
  __shared__ c32 S[1024];
  __shared__ c32 zz[1088];
  __shared__ float corr[1024];
#pragma unroll
  for (int k = 0; k < 4; ++k) {
    int i = tid + k * 256;
    twl[ZIDX(i)] = twg[i];
  }
  c32 sa = {0.f, 0.f}, sb = {0.f, 0.f}, s5 = {0.f, 0.f};
  const c32* pbase = part + (size_t)b * 32 * 513;
  for (int p = 0; p < 32; ++p) {
    const c32* pp = pbase + p * 513;
    sa = cadd(sa, pp[tid]);
    sb = cadd(sb, pp[tid + 256]);
    if (tid == 0) s5 = cadd(s5, pp[512]);
  }
  S[tid] = sa;
  S[tid + 256] = sb;
  if (tid == 0) S[512] = s5;
  if (tid > 0) S[1024 - tid] = c32{sa.x, -sa.y};  // 769..1023
  S[768 - tid] = c32{sb.x, -sb.y};                // 513..768
  __syncthreads();
#pragma unroll
  for (int k = 0; k < 4; ++k) {
    int t = tid + k * 256;
    zz[ZIDX(drev4(t))] = S[t];
  }
  __syncthreads();
  for (int s = 0; s < 5; ++s) {
    fft_stage<1>(&zz[0], twl, tid, s);
    __syncthreads();
  }
  const float scl = 1.0f / (1024.0f * 512.0f);  // irfft 1/N * mean over 512 dims
#pragma unroll
  for (int k = 0; k < 4; ++k) {
    int t = tid + k * 256;
    corr[t] = zz[ZIDX(t)].x * scl;
  }
  __syncthreads();
  __shared__ float swv[4];
  __shared__ int swi[4];
  __shared__ float selv[CTOPK];
  __shared__ int seli[CTOPK];
  int wid = tid >> 6, lane = tid & 63;
  for (int k = 0; k < CTOPK; ++k) {
    float bv = -INFINITY;
    int bi = 0;
#pragma unroll
    for (int q = 0; q < 4; ++q) {
      int idx = tid + q * 256;
      float v = corr[idx];
      if (v > bv || (v == bv && idx < bi)) { bv = v; bi = idx; }
    }
#pragma unroll
    for (int off = 32; off > 0; off >>= 1) {
      float ov = __shfl_down(bv, off);
      int oi = __shfl_down(bi, off);
      if (ov > bv || (ov == bv && oi < bi)) { bv = ov; bi = oi; }
    }
    if (lane == 0) { swv[wid] = bv; swi[wid] = bi; }
    __syncthreads();
    if (tid == 0) {
      float mvv = swv[0];
      int mi = swi[0];
      for (int q2 = 1; q2 < 4; ++q2)
        if (swv[q2] > mvv || (swv[q2] == mvv && swi[q2] < mi)) { mvv = swv[q2]; mi = swi[q2]; }
      selv[k] = mvv;
      seli[k] = mi;
      corr[mi] = -INFINITY;
    }
    __syncthreads();
  }
  if (tid == 0) {
    float mx = selv[0], sum = 0.f, e[CTOPK];
    for (int k = 0; k < CTOPK; ++k) {
      e[k] = expf(selv[k] - mx);
      sum += e[k];
    }
    float inv = 1.0f / sum;
    for (int k = 0; k < CTOPK; ++k) {
      wts[b * CTOPK + k] = e[k] * inv;
      idxs[b * CTOPK + k] = seli[k];
    }
  }
}

// ---------------- delay aggregation: bf16 V [Mc][512]; XCD-swizzled -----------------
__global__ __launch_bounds__(128) void k_agg(const ushort* __restrict__ Vf,
                                             const float* __restrict__ wts,
                                             const int* __restrict__ idxs,
                                             ushort* __restrict__ out2) {
  int nb = gridDim.x;
  int blk = blockIdx.x;
  int row = (blk & 7) * (nb >> 3) + (blk >> 3);
  int b = row >> 10, t = row & 1023;
  int d0 = threadIdx.x * 4;
  const ushort* Vb = Vf + (size_t)b * CT * 512;
  float4 acc = {0.f, 0.f, 0.f, 0.f};
#pragma unroll
  for (int k = 0; k < CTOPK; ++k) {
    float w = wts[b * CTOPK + k];
    int r = t + idxs[b * CTOPK + k];
    if (r >= CT) r -= CT;
    ushort4 v = *(const ushort4*)(Vb + (size_t)r * 512 + d0);
    acc.x += w * bf16f(v.x);
    acc.y += w * bf16f(v.y);
    acc.z += w * bf16f(v.z);
    acc.w += w * bf16f(v.w);
  }
  ushort4 hv = {bf16r(acc.x), bf16r(acc.y), bf16r(acc.z), bf16r(acc.w)};
  *(ushort4*)(out2 + (size_t)row * CD + d0) = hv;
}

// ---------------- fused LN + series decomp, SLIDING WINDOW --------------------------
__global__ __launch_bounds__(256) void k_dec2(const float* __restrict__ X,
                                              const c32* __restrict__ st,
                                              const float* __restrict__ g,
                                              float* __restrict__ out,
                                              ushort* __restrict__ out2) {
  int b = blockIdx.y;
  int t0 = blockIdx.x * 64;
  int tid = threadIdx.x;
  const float* xb = X + (size_t)b * CT * CD;
  const c32* sb = st + (size_t)b * CT;
  float g0v = g[tid], g1v = g[tid + 256];
  float s0 = 0.f, s1 = 0.f;
#pragma unroll
  for (int j = -12; j <= 12; ++j) {
    int u = t0 + j;
    u = u < 0 ? 0 : (u > CT - 1 ? CT - 1 : u);
    c32 ms = sb[u];
    s0 += (xb[(size_t)u * CD + tid] - ms.x) * ms.y;
    s1 += (xb[(size_t)u * CD + tid + 256] - ms.x) * ms.y;
  }
  const float inv = 1.0f / 25.0f;
  for (int tt = 0; tt < 64; ++tt) {
    int t = t0 + tt;
    c32 mc = sb[t];
    float z0 = (xb[(size_t)t * CD + tid] - mc.x) * mc.y;
    float z1 = (xb[(size_t)t * CD + tid + 256] - mc.x) * mc.y;
    float o0 = g0v * (z0 - s0 * inv);
    float o1 = g1v * (z1 - s1 * inv);
    size_t ro = (size_t)(b * CT + t) * CD;
    out[ro + tid] = o0;
    out[ro + tid + 256] = o1;
    out2[ro + tid] = bf16r(o0);
    out2[ro + tid + 256] = bf16r(o1);
    int ua = t + 13;
    ua = ua > CT - 1 ? CT - 1 : ua;
    int ur = t - 12;
    ur = ur < 0 ? 0 : ur;
    c32 ma = sb[ua], mr = sb[ur];
    s0 += (xb[(size_t)ua * CD + tid] - ma.x) * ma.y -
          (xb[(size_t)ur * CD + tid] - mr.x) * mr.y;
    s1 += (xb[(size_t)ua * CD + tid + 256] - ma.x) * ma.y -
          (xb[(size_t)ur * CD + tid + 256] - mr.x) * mr.y;
  }
}

// ---------------- partial time-mean: grid (Bc, 8), coalesced ------------------------
__global__ __launch_bounds__(256) void k_meanp(const float* __restrict__ X,
                                               float* __restrict__ part) {
  int b = blockIdx.x, g = blockIdx.y, tid = threadIdx.x;
  const float* xb = X + (size_t)b * CT * CD + (size_t)g * 128 * CD;
  float a0 = 0.f, a1 = 0.f;
  for (int r = 0; r < 128; ++r) {
    a0 += xb[(size_t)r * CD + tid];
    a1 += xb[(size_t)r * CD + tid + 256];
  }
  part[((size_t)b * 8 + g) * CD + tid] = a0;
  part[((size_t)b * 8 + g) * CD + tid + 256] = a1;
}

// ---------------- final head: mean-combine + 2-layer MLP ----------------------------
__global__ __launch_bounds__(256) void k_headf(const float* __restrict__ part,
                                               const float* __restrict__ w1,
                                               const float* __restrict__ b1,
                                               const float* __restrict__ w2,
                                               const float* __restrict__ b2,
                                               float* __restrict__ out) {
  int b = blockIdx.x, tid = threadIdx.x;
  __shared__ float f[CD];
  __shared__ float hid[CFCH];
  for (int d = tid; d < CD; d += 256) {
    float s = 0.f;
#pragma unroll
    for (int g = 0; g < 8; ++g) s += part[((size_t)b * 8 + g) * CD + d];
    f[d] = s * (1.0f / CT);
  }
  __syncthreads();
  float a = b1[tid];
  for (int d = 0; d < CD; ++d) a += f[d] * w1[d * CFCH + tid];
  hid[tid] = fmaxf(a, 0.f);
  __syncthreads();
  if (tid < CNC) {
    float a2 = b2[tid];
    for (int j = 0; j < CFCH; ++j) a2 += hid[j] * w2[j * CNC + tid];
    out[b * CNC + tid] = a2;
  }
}

// =====================================================================================
extern "C" void kernel_launch(void* const* d_in, const int* in_sizes, int n_in,
                              void* d_out, int out_size, void* d_ws, size_t ws_size,
                              hipStream_t stream) {
  const float* x = (const float*)d_in[0];
  const float* emb_w = (const float*)d_in[1];
  const float* emb_g = (const float*)d_in[2];
  const float* emb_b = (const float*)d_in[3];
  const float* attn_w = (const float*)d_in[4];
  const float* attn_b = (const float*)d_in[5];
  const float* ln_g = (const float*)d_in[6];
  const float* ln_bb = (const float*)d_in[7];
  const float* fc1_w = (const float*)d_in[8];
  const float* fc1_b = (const float*)d_in[9];
  const float* fc2_w = (const float*)d_in[10];
  const float* fc2_b = (const float*)d_in[11];
  const float* hw1 = (const float*)d_in[12];
  const float* hb1 = (const float*)d_in[13];
  const float* hw2 = (const float*)d_in[14];
  const float* hb2 = (const float*)d_in[15];
  float* outp = (float*)d_out;

  // per-layer bf16 weights (ushorts): wq,wk,wv (contig => fused QKV), wo, w1, w2
  const size_t WQ = 262144ULL;                         // 512*512
  const size_t LW = 4 * WQ + 1048576ULL + 1048576ULL;  // 3,145,728 ushorts
  const size_t W2TOT = CL * LW;

  const size_t FIXED_B = W2TOT * 2                     // bf16 weights
                         + (size_t)CT * CD * 4         // postab
                         + 2 * (size_t)CB * CCH * 4    // sc,lg
                         + 2 * (size_t)CB * CTOPK * 4  // wts,idxs
                         + (size_t)CB * 8 * CD * 4     // mean partials
                         + 1024 * 8                    // twiddles
                         + 4096;
  const size_t PERB = 2ULL * CT * CD * 4 + (size_t)CT * CD * 2 + (size_t)CT * 2048 * 2 +
                      (size_t)32 * 513 * 8 + (size_t)CT * 8 + (size_t)CT * 64;
  int Bc = CB;
  while (Bc > 1) {
    if ((size_t)Bc * PERB + FIXED_B <= ws_size) break;
    Bc >>= 1;
  }
  const size_t CHF = (size_t)Bc * CT * CD;

  char* wsp = (char*)d_ws;
  float* P0 = (float*)wsp;     wsp += CHF * 4;
  float* P1 = (float*)wsp;     wsp += CHF * 4;
  ushort* U0 = (ushort*)wsp;   wsp += CHF * 2;            // h2 / agg-out / d2
  ushort* U1 = (ushort*)wsp;   wsp += (size_t)Bc * CT * 2048 * 2;  // fp32 QT / bf16 f2
  ushort* W2b = (ushort*)wsp;  wsp += W2TOT * 2;
  float* postab = (float*)wsp; wsp += (size_t)CT * CD * 4;
  float* scb = (float*)wsp;    wsp += (size_t)CB * CCH * 4;
  float* lgb = (float*)wsp;    wsp += (size_t)CB * CCH * 4;
  float* wtb = (float*)wsp;    wsp += (size_t)CB * CTOPK * 4;
  int* idb = (int*)wsp;        wsp += (size_t)CB * CTOPK * 4;
  float* partb = (float*)wsp;  wsp += (size_t)CB * 8 * CD * 4;
  c32* twc = (c32*)wsp;        wsp += 1024 * sizeof(c32);
  c32* partc = (c32*)wsp;      wsp += (size_t)Bc * 32 * 513 * sizeof(c32);
  c32* stb = (c32*)wsp;        wsp += (size_t)Bc * CT * sizeof(c32);
  c32* st8b = (c32*)wsp;       wsp += (size_t)Bc * CT * 8 * sizeof(c32);

  // ---- convert all weights to transposed bf16 [N][K], once per call ----
  for (int l = 0; l < CL; ++l) {
    ushort* wq2 = W2b + l * LW;      // [1536][512] fused QKV (q,k,v contiguous)
    ushort* w12 = wq2 + 4 * WQ;
    ushort* w22 = w12 + 1048576;
    k_cvtw<<<dim3(CD / 32, CD / 32, 4), 256, 0, stream>>>(
        attn_w + (size_t)l * 4 * CD * CD, wq2, CD, CD);
    k_cvtw<<<dim3(CFFN / 32, CD / 32, 1), 256, 0, stream>>>(
        fc1_w + (size_t)l * CD * CFFN, w12, CD, CFFN);
    k_cvtw<<<dim3(CD / 32, CFFN / 32, 1), 256, 0, stream>>>(
        fc2_w + (size_t)l * CFFN * CD, w22, CFFN, CD);
  }

  k_scale<<<CB, 256, 0, stream>>>(x, scb, lgb);
  k_postab<<<CT, 512, 0, stream>>>(postab);
  k_twid<<<4, 256, 0, stream>>>(twc);

  for (int b0 = 0; b0 < CB; b0 += Bc) {
    const int Mc = Bc * CT;

    float* HP = P0;  // h fp32 (stable across layers; no swap needed)
    float* SA = P1;  // scratch: bf16 V / attn-out / ffn-out

    k_embed<<<Mc, 128, 0, stream>>>(x + (size_t)b0 * CT * CCH, scb + b0 * CCH,
                                    lgb + b0 * CCH, emb_w, postab, emb_g, emb_b,
                                    HP, U0);

    for (int l = 0; l < CL; ++l) {
      const float* bqkv = attn_b + (size_t)l * 4 * CD;  // q,k,v biases contiguous
      const float* bo = attn_b + (size_t)(l * 4 + 3) * CD;
      const float* g0 = ln_g + (size_t)(l * 2 + 0) * CD;
      const float* g1 = ln_g + (size_t)(l * 2 + 1) * CD;
      const float* B1 = fc1_b + (size_t)l * CFFN;
      const float* B2f = fc2_b + (size_t)l * CD;
      const ushort* wq2 = W2b + l * LW;
      const ushort* wo2 = wq2 + 3 * WQ;
      const ushort* w12 = wq2 + 4 * WQ;
      const ushort* w22 = w12 + 1048576;

      // fused QKV projection: fp32 Q,K TRANSPOSED -> U1 QT[1024][Mc]; bf16 V -> SA
      k_gemm3<7><<<dim3(1536 / 128, Mc / 128), 256, 0, stream>>>(
          U0, wq2, bqkv, nullptr, (float*)U1, (ushort*)SA, nullptr, CD, CD, Mc, CD);
      // packed-real FFT autocorrelation: product spectra -> partc
      k_fft<<<dim3(32, Bc), 256, 0, stream>>>((const float*)U1, twc, partc, Mc);
      // spectrum reduce + irfft + top-20 + softmax
      k_spectopk<<<Bc, 256, 0, stream>>>(partc, twc, wtb, idb);
      // delay aggregation (bf16 V in SA) -> U0 bf16
      k_agg<<<Mc, 128, 0, stream>>>((const ushort*)SA, wtb, idb, U0);
      // O proj (+residual HP) -> SA, with fused LN-stats partials
      k_gemm3<3><<<dim3(CD / 128, Mc / 128), 256, 0, stream>>>(
          U0, wo2, bo, HP, (float*)SA, nullptr, (ushort*)st8b, CD, CD, CD, CD);
      k_finst<<<Mc / 256, 256, 0, stream>>>(st8b, stb);
      k_dec2<<<dim3(CT / 64, Bc), 256, 0, stream>>>((float*)SA, stb, g0, HP, U0);
      // FFN: FC1 (GELU -> bf16 f2 = U1 [Mc][2048]), FC2 (+res HP, stats) -> SA
      k_gemm3<1><<<dim3(CFFN / 128, Mc / 128), 256, 0, stream>>>(
          U0, w12, B1, nullptr, nullptr, U1, nullptr, CD, CD, CFFN, CD);
      k_gemm3<3><<<dim3(CD / 128, Mc / 128), 256, 0, stream>>>(
          U1, w22, B2f, HP, (float*)SA, nullptr, (ushort*)st8b, CFFN, CFFN, CD, CFFN);
      k_finst<<<Mc / 256, 256, 0, stream>>>(st8b, stb);
      k_dec2<<<dim3(CT / 64, Bc), 256, 0, stream>>>((float*)SA, stb, g1, HP, U0);
    }

    k_meanp<<<dim3(Bc, 8), 256, 0, stream>>>(HP, partb + (size_t)b0 * 8 * CD);
    k_headf<<<Bc, 256, 0, stream>>>(partb + (size_t)b0 * 8 * CD, hw1, hb1, hw2, hb2,
                                    outp + (size_t)b0 * CNC);
  }
}

// Round 9
// 2731.243 us; speedup vs baseline: 1.0486x; 1.0186x over previous
//
#include <hip/hip_runtime.h>
#include <math.h>

#define CB 64      // batch
#define CT 1024    // time
#define CCH 12     // channels
#define CD 512     // d_model
#define CL 2       // layers
#define CFFN 2048
#define CFCH 256
#define CNC 5
#define CTOPK 20
#define CEPS 1e-5f

typedef __attribute__((ext_vector_type(8))) short bfrag;
typedef __attribute__((ext_vector_type(4))) float ffrag;

__device__ inline ushort bf16r(float f) {
  unsigned u = __float_as_uint(f);
  unsigned r = (u + 0x7FFFu + ((u >> 16) & 1u)) >> 16;
  return (ushort)r;
}
__device__ inline float bf16f(ushort h) { return __uint_as_float(((unsigned)h) << 16); }

// async 16B global->LDS (lds dest = wave-uniform base + lane*16)
__device__ __forceinline__ void gld16(const ushort* g, ushort* l) {
  __builtin_amdgcn_global_load_lds((__attribute__((address_space(1))) void*)g,
                                   (__attribute__((address_space(3))) void*)l,
                                   16, 0, 0);
}

// ---------------- complex helpers ----------------
struct c32 { float x, y; };
__device__ inline c32 cadd(c32 a, c32 b) { return c32{a.x + b.x, a.y + b.y}; }
__device__ inline c32 csub(c32 a, c32 b) { return c32{a.x - b.x, a.y - b.y}; }
__device__ inline c32 cmul(c32 a, c32 b) {  // a*b
  return c32{a.x * b.x - a.y * b.y, a.x * b.y + a.y * b.x};
}
__device__ inline c32 cmulj(c32 a, c32 b) {  // a*conj(b)
  return c32{a.x * b.x + a.y * b.y, a.y * b.x - a.x * b.y};
}
__device__ inline c32 mineg_i(c32 a) { return c32{a.y, -a.x}; }  // -i*a
__device__ inline c32 mul_i(c32 a) { return c32{-a.y, a.x}; }    // +i*a

// LDS padding: +1 c32 per 16 -> balanced 4-way (wave64 minimum) on every
// stage stride and on the digit-reversed scatter.
#define ZIDX(p) ((p) + ((p) >> 4))

// base-4 digit reversal of 5 digits (N=1024=4^5); involution
__device__ inline int drev4(int t) {
  return ((t & 3) << 8) | (((t >> 2) & 3) << 6) | (((t >> 4) & 3) << 4) |
         (((t >> 6) & 3) << 2) | ((t >> 8) & 3);
}

// radix-4 DIT stage s (in-place; input digit-reversed, output natural).
template <int INV>
__device__ inline void fft_stage(c32* zz, const c32* twl, int tid, int s) {
  int L = 1 << (2 * s);
  int j = tid & (L - 1);
  int g = tid >> (2 * s);
  int p0 = (g << (2 * s + 2)) + j;
  int tb = j << (8 - 2 * s);
  c32 w1 = twl[ZIDX(tb)], w2 = twl[ZIDX(2 * tb)], w3 = twl[ZIDX(3 * tb)];
  c32 b0 = zz[ZIDX(p0)], b1 = zz[ZIDX(p0 + L)], b2 = zz[ZIDX(p0 + 2 * L)],
      b3 = zz[ZIDX(p0 + 3 * L)];
  if (INV) { b1 = cmulj(b1, w1); b2 = cmulj(b2, w2); b3 = cmulj(b3, w3); }
  else     { b1 = cmul(b1, w1);  b2 = cmul(b2, w2);  b3 = cmul(b3, w3); }
  c32 e0 = cadd(b0, b2), e1 = csub(b0, b2), e2 = cadd(b1, b3), e3 = csub(b1, b3);
  c32 e3r = INV ? mul_i(e3) : mineg_i(e3);
  zz[ZIDX(p0)] = cadd(e0, e2);
  zz[ZIDX(p0 + L)] = cadd(e1, e3r);
  zz[ZIDX(p0 + 2 * L)] = csub(e0, e2);
  zz[ZIDX(p0 + 3 * L)] = csub(e1, e3r);
}

// unpack packed-real FFT (z=q+ik, ZIDX-padded) at bin w; accumulate P = Qf*conj(Kf)
__device__ inline void unp_acc(const c32* zf, int w, c32& acc) {
  int wc = (1024 - w) & 1023;
  c32 Z1 = zf[ZIDX(w)];
  c32 Z2r = zf[ZIDX(wc)];
  c32 Z2 = c32{Z2r.x, -Z2r.y};                       // conj(Z[N-w])
  c32 Qf = c32{0.5f * (Z1.x + Z2.x), 0.5f * (Z1.y + Z2.y)};
  c32 M = c32{Z1.x - Z2.x, Z1.y - Z2.y};
  c32 Kf = c32{0.5f * M.y, -0.5f * M.x};             // -0.5i*M
  acc.x += Qf.x * Kf.x + Qf.y * Kf.y;                // Qf*conj(Kf)
  acc.y += Qf.y * Kf.x - Qf.x * Kf.y;
}

// ---------------- twiddle table, fp64-accurate (one-time) ---------------------------
__global__ __launch_bounds__(256) void k_twid(c32* __restrict__ tw) {
  int j = blockIdx.x * 256 + threadIdx.x;  // 0..1023
  double a = -2.0 * 3.14159265358979323846 * (double)j / 1024.0;
  tw[j] = c32{(float)cos(a), (float)sin(a)};
}

// ---------------- mean-abs scaler ----------------
__global__ __launch_bounds__(256) void k_scale(const float* __restrict__ x,
                                               float* __restrict__ sc,
                                               float* __restrict__ lg) {
  int b = blockIdx.x, tid = threadIdx.x;
  float acc[CCH];
#pragma unroll
  for (int c = 0; c < CCH; ++c) acc[c] = 0.f;
  const float* xb = x + (size_t)b * CT * CCH;
  for (int t = tid; t < CT; t += 256) {
    const float* row = xb + t * CCH;
#pragma unroll
    for (int c = 0; c < CCH; ++c) acc[c] += fabsf(row[c]);
  }
  __shared__ float red[256][CCH];
#pragma unroll
  for (int c = 0; c < CCH; ++c) red[tid][c] = acc[c];
  __syncthreads();
  for (int off = 128; off > 0; off >>= 1) {
    if (tid < off) {
#pragma unroll
      for (int c = 0; c < CCH; ++c) red[tid][c] += red[tid + off][c];
    }
    __syncthreads();
  }
  if (tid < CCH) {
    float s = fmaxf(red[0][tid] * (1.0f / CT), 1e-10f);
    sc[b * CCH + tid] = s;
    lg[b * CCH + tid] = logf(s);
  }
}

// ---------------- sinusoidal position table (f64, matches np) ----------------
__global__ __launch_bounds__(512) void k_postab(float* __restrict__ pos) {
  int t = blockIdx.x;
  int d = threadIdx.x;
  double v;
  if (d < 256) {
    double w = pow(10000.0, -((double)d) / 256.0);
    v = sin((double)t * w);
  } else {
    double w = pow(10000.0, -((double)(d - 256)) / 256.0);
    v = cos((double)t * w);
  }
  pos[(size_t)t * CD + d] = (float)v;
}

// ---------------- embedding + LN fused; writes fp32 h AND bf16 h2 -------------------
__global__ __launch_bounds__(128) void k_embed(const float* __restrict__ x,
                                               const float* __restrict__ sc,
                                               const float* __restrict__ lg,
                                               const float* __restrict__ W,
                                               const float* __restrict__ postab,
                                               const float* __restrict__ g,
                                               const float* __restrict__ beta,
                                               float* __restrict__ h,
                                               ushort* __restrict__ h2) {
  int row = blockIdx.x;  // local: b*T + t
  int b = row >> 10, t = row & 1023;
  int tid = threadIdx.x;
  __shared__ float xs[CCH], ls[CCH];
  if (tid < CCH) {
    float s = sc[b * CCH + tid];
    xs[tid] = x[(size_t)row * CCH + tid] / s;
    ls[tid] = lg[b * CCH + tid];
  }
  __syncthreads();
  int d0 = tid * 4;
  float4 p = *(const float4*)(postab + (size_t)t * CD + d0);
  float v0 = p.x, v1 = p.y, v2 = p.z, v3 = p.w;
#pragma unroll
  for (int c = 0; c < CCH; ++c) {
    float xc = xs[c], lc = ls[c];
    float4 w0 = *(const float4*)(W + (size_t)c * CD + d0);
    float4 w1 = *(const float4*)(W + (size_t)(24 + c) * CD + d0);
    v0 += xc * w0.x + lc * w1.x;
    v1 += xc * w0.y + lc * w1.y;
    v2 += xc * w0.z + lc * w1.z;
    v3 += xc * w0.w + lc * w1.w;
  }
  float s1 = v0 + v1 + v2 + v3;
  float s2 = v0 * v0 + v1 * v1 + v2 * v2 + v3 * v3;
  for (int off = 32; off > 0; off >>= 1) {
    s1 += __shfl_down(s1, off);
    s2 += __shfl_down(s2, off);
  }
  __shared__ float ws1[2], ws2[2], mv[2];
  int wid = tid >> 6, lane = tid & 63;
  if (lane == 0) { ws1[wid] = s1; ws2[wid] = s2; }
  __syncthreads();
  if (tid == 0) {
    float S1 = ws1[0] + ws1[1], S2 = ws2[0] + ws2[1];
    float mu = S1 * (1.0f / CD);
    float var = S2 * (1.0f / CD) - mu * mu;
    mv[0] = mu;
    mv[1] = 1.0f / sqrtf(var + CEPS);
  }
  __syncthreads();
  float mu = mv[0], ri = mv[1];
  float4 gg = *(const float4*)(g + d0);
  float4 bb = *(const float4*)(beta + d0);
  float4 o;
  o.x = (v0 - mu) * ri * gg.x + bb.x;
  o.y = (v1 - mu) * ri * gg.y + bb.y;
  o.z = (v2 - mu) * ri * gg.z + bb.z;
  o.w = (v3 - mu) * ri * gg.w + bb.w;
  *(float4*)(h + (size_t)row * CD + d0) = o;
  ushort4 hv = {bf16r(o.x), bf16r(o.y), bf16r(o.z), bf16r(o.w)};
  *(ushort4*)(h2 + (size_t)row * CD + d0) = hv;
}

// ---------------- weight convert+transpose: W[K][N] fp32 -> W2[N][K] bf16 -----------
// blockIdx.z batches multiple same-shape matrices (stride K*N on both sides).
__global__ __launch_bounds__(256) void k_cvtw(const float* __restrict__ W,
                                              ushort* __restrict__ W2,
                                              int K, int N) {
  __shared__ float tile[32][33];
  size_t zoff = (size_t)blockIdx.z * K * N;
  int tx = threadIdx.x & 31, ty = threadIdx.x >> 5;  // ty 0..7
  int n0 = blockIdx.x * 32, k0 = blockIdx.y * 32;
#pragma unroll
  for (int r = 0; r < 4; ++r)
    tile[ty * 4 + r][tx] = W[zoff + (size_t)(k0 + ty * 4 + r) * N + n0 + tx];
  __syncthreads();
#pragma unroll
  for (int r = 0; r < 4; ++r) {
    int nl = ty * 4 + r, kl = tx;
    W2[zoff + (size_t)(n0 + nl) * K + k0 + kl] = bf16r(tile[kl][nl]);
  }
}

// ---------------- bf16 MFMA GEMM, 128x128 tile, BK=64, double-buffered pipeline -----
// A: [M][lda] bf16 k-contig rows; W: [N][ldb] bf16 k-contig rows.
// R8 analysis: 2-phase K-loop pays a fixed ~1600-cycle stall per iteration
// (vmcnt drain + barrier), occupancy-insensitive (R5). BK 32->64 halves NK ->
// halves total stall while MFMA/ds-read time is unchanged. LDS 64KB (2buf x 2mat
// x 128x64x2B) keeps double-buffering (m132's BK=128 regression lost dbuf).
// Staging: 8-row gld16 groups; source chunk (lane&7)^(lane>>3); 8 gld16/wave/tile;
// steady wait vmcnt(8). Read: chunk cq=ksub*4+quad at slot cq^(row&7) -> 2-way
// bank access (free). Same XCD-chunked bijective grid swizzle.
// EPI: 0=bias->fp32  1=bias+GELU->bf16  2=bias+residual->fp32
//      3=bias+residual->fp32 + per-row LN-stats partials (Cs2 = st8[M][8] c32)
//      7=QKV: cols<1024 -> TRANSPOSED fp32 Cf[col][ldc], cols>=1024 -> V bf16
template <int EPI>
__global__ __launch_bounds__(256) void k_gemm3(const ushort* __restrict__ A,
                                               const ushort* __restrict__ W,
                                               const float* __restrict__ bias,
                                               const float* __restrict__ R,
                                               float* __restrict__ Cf,
                                               ushort* __restrict__ Cs,
                                               ushort* __restrict__ Cs2,
                                               int lda, int ldb, int ldc, int K) {
  __shared__ ushort AhS[2][128 * 64];
  __shared__ ushort BhS[2][128 * 64];
  int tid = threadIdx.x;
  int nx = gridDim.x;
  int nwg = nx * gridDim.y;
  int flat = blockIdx.y * nx + blockIdx.x;
  int sw = (flat & 7) * (nwg >> 3) + (flat >> 3);
  int n0 = (sw % nx) * 128, m0 = (sw / nx) * 128;
  int wid = __builtin_amdgcn_readfirstlane(tid >> 6);
  int lane = tid & 63;
  int lr8 = lane >> 3;                             // 0..7: row in an 8-row gld16 group
  int lc = ((lane & 7) ^ lr8) * 8;                 // swizzled source chunk (ushorts)
  int wm = wid >> 1, wn = wid & 1;
  int mOff = wm * 64, nOff = wn * 64;
  int quad = lane >> 4, l16 = lane & 15;

  const ushort* pA = A + (size_t)(m0 + wid * 32 + lr8) * lda + lc;
  const ushort* pB = W + (size_t)(n0 + wid * 32 + lr8) * ldb + lc;
  const int NK = K >> 6;

  ffrag acc[4][4];
#pragma unroll
  for (int i = 0; i < 4; ++i)
#pragma unroll
    for (int j = 0; j < 4; ++j) acc[i][j] = (ffrag)(0.f);

#define ISSUE(t, buf)                                                        \
  {                                                                          \
    int kk = (t) << 6;                                                       \
    ushort* lA = &AhS[buf][(wid * 32) * 64];                                 \
    ushort* lB = &BhS[buf][(wid * 32) * 64];                                 \
    gld16(pA + kk, lA);                                                      \
    gld16(pA + (size_t)8 * lda + kk, lA + 8 * 64);                           \
    gld16(pA + (size_t)16 * lda + kk, lA + 16 * 64);                         \
    gld16(pA + (size_t)24 * lda + kk, lA + 24 * 64);                         \
    gld16(pB + kk, lB);                                                      \
    gld16(pB + (size_t)8 * ldb + kk, lB + 8 * 64);                           \
    gld16(pB + (size_t)16 * ldb + kk, lB + 16 * 64);                         \
    gld16(pB + (size_t)24 * ldb + kk, lB + 24 * 64);                         \
  }

  ISSUE(0, 0);
  ISSUE(1, 1);
  for (int k = 0; k < NK; ++k) {
    if (k + 1 < NK) {
      asm volatile("s_waitcnt vmcnt(8)\n\ts_barrier" ::: "memory");
    } else {
      asm volatile("s_waitcnt vmcnt(0)\n\ts_barrier" ::: "memory");
    }
    int buf = k & 1;
#pragma unroll
    for (int s = 0; s < 2; ++s) {
      int cq = s * 4 + quad;
      bfrag ah[4], bh[4];
#pragma unroll
      for (int i = 0; i < 4; ++i) {
        int row = mOff + i * 16 + l16;
        ah[i] = *(const bfrag*)&AhS[buf][row * 64 + (cq ^ (row & 7)) * 8];
      }
#pragma unroll
      for (int j = 0; j < 4; ++j) {
        int row = nOff + j * 16 + l16;
        bh[j] = *(const bfrag*)&BhS[buf][row * 64 + (cq ^ (row & 7)) * 8];
      }
#pragma unroll
      for (int i = 0; i < 4; ++i)
#pragma unroll
        for (int j = 0; j < 4; ++j)
          acc[i][j] = __builtin_amdgcn_mfma_f32_16x16x32_bf16(ah[i], bh[j], acc[i][j], 0, 0, 0);
    }
    asm volatile("s_barrier" ::: "memory");
    if (k + 2 < NK) ISSUE(k + 2, buf);
  }
#undef ISSUE

  // C tile layout: col = lane&15, row = quad*4 + reg (verified R3-R10)
  if (EPI == 3) {
    c32* st8 = (c32*)Cs2;
#pragma unroll
    for (int i = 0; i < 4; ++i) {
#pragma unroll
      for (int r = 0; r < 4; ++r) {
        int row = m0 + mOff + i * 16 + quad * 4 + r;
        float s1 = 0.f, s2 = 0.f;
#pragma unroll
        for (int j = 0; j < 4; ++j) {
          int col = n0 + nOff + j * 16 + l16;
          float vv = acc[i][j][r] + bias[col] + R[(size_t)row * ldc + col];
          Cf[(size_t)row * ldc + col] = vv;
          s1 += vv;
          s2 += vv * vv;
        }
#pragma unroll
        for (int off = 8; off > 0; off >>= 1) {
          s1 += __shfl_xor(s1, off);
          s2 += __shfl_xor(s2, off);
        }
        if (l16 == 0) st8[(size_t)row * 8 + (n0 >> 6) + wn] = c32{s1, s2};
      }
    }
  } else {
#pragma unroll
    for (int j = 0; j < 4; ++j) {
      int col = n0 + nOff + j * 16 + l16;
      float bcol = bias[col];
#pragma unroll
      for (int i = 0; i < 4; ++i) {
        int rowb = m0 + mOff + i * 16 + quad * 4;
        if (EPI == 7) {
          if (col < 1024) {
            float4 o = {acc[i][j][0] + bcol, acc[i][j][1] + bcol,
                        acc[i][j][2] + bcol, acc[i][j][3] + bcol};
            *(float4*)(Cf + (size_t)col * ldc + rowb) = o;
          } else {
#pragma unroll
            for (int r = 0; r < 4; ++r)
              Cs[(size_t)(rowb + r) * 512 + (col - 1024)] = bf16r(acc[i][j][r] + bcol);
          }
        } else {
#pragma unroll
          for (int r = 0; r < 4; ++r) {
            int row = rowb + r;
            float vv = acc[i][j][r] + bcol;
            if (EPI == 1) vv = 0.5f * vv * (1.0f + erff(vv * 0.7071067811865475f));
            if (EPI == 2) vv += R[(size_t)row * ldc + col];
            if (EPI == 1) {
              Cs[(size_t)row * ldc + col] = bf16r(vv);
            } else {
              Cf[(size_t)row * ldc + col] = vv;
            }
          }
        }
      }
    }
  }
}

// ---------------- combine st8 partials -> (mu, 1/sigma) per row ---------------------
__global__ __launch_bounds__(256) void k_finst(const c32* __restrict__ st8,
                                               c32* __restrict__ st) {
  int row = blockIdx.x * 256 + threadIdx.x;
  float s1 = 0.f, s2 = 0.f;
#pragma unroll
  for (int p = 0; p < 8; ++p) {
    c32 v = st8[(size_t)row * 8 + p];
    s1 += v.x;
    s2 += v.y;
  }
  float mu = s1 * (1.0f / CD);
  float var = s2 * (1.0f / CD) - mu * mu;
  st[row] = c32{mu, 1.0f / sqrtf(var + CEPS)};
}

// ---------------- autocorrelation via packed-real FFT (transposed input) ------------
__global__ __launch_bounds__(256) void k_fft(const float* __restrict__ QT,
                                             const c32* __restrict__ twg,
                                             c32* __restrict__ part, int Mc) {
  __shared__ c32 z[4][1088];
  __shared__ c32 twl[1088];
  int dg = blockIdx.x, zb = blockIdx.y, tid = threadIdx.x;
#pragma unroll
  for (int k = 0; k < 4; ++k) {
    int i = tid + k * 256;
    twl[ZIDX(i)] = twg[i];
  }
  c32 pa = {0.f, 0.f}, pb = {0.f, 0.f}, p5 = {0.f, 0.f};
  for (int i = 0; i < 4; ++i) {
    int d0 = dg * 16 + i * 4;
#pragma unroll
    for (int f = 0; f < 4; ++f) {
      const float* qr = QT + (size_t)(d0 + f) * Mc + (size_t)zb * 1024;
      const float* kr = QT + (size_t)(512 + d0 + f) * Mc + (size_t)zb * 1024;
#pragma unroll
      for (int k = 0; k < 4; ++k) {
        int t = tid + k * 256;
        z[f][ZIDX(drev4(t))] = c32{qr[t], kr[t]};
      }
    }
    __syncthreads();  // also covers twl on first iter
    for (int s = 0; s < 5; ++s) {
#pragma unroll
      for (int f = 0; f < 4; ++f) fft_stage<0>(&z[f][0], twl, tid, s);
      __syncthreads();
    }
#pragma unroll
    for (int f = 0; f < 4; ++f) {
      unp_acc(&z[f][0], tid, pa);
      unp_acc(&z[f][0], tid + 256, pb);
      if (tid == 0) unp_acc(&z[f][0], 512, p5);
    }
    __syncthreads();  // before next iter overwrites z
  }
  c32* po = part + ((size_t)zb * 32 + dg) * 513;
  po[tid] = pa;
  po[tid + 256] = pb;
  if (tid == 0) po[512] = p5;
}

// ---------------- spectrum reduce + irfft + top-20 + softmax (fused) ----------------
__global__ __launch_bounds__(256) void k_spectopk(const c32* __restrict__ part,
                                                  const c32* __restrict__ twg,
                                                  float* __restrict__ wts,
                                                  int* __restrict__ idxs) {
  int b = blockIdx.x, tid = threadIdx.x;
  __shared__ c32 twl[1088];
  __shared__ c32 S[1024];
  __shared__ c32 zz[1088];
  __shared__ float corr[1024];
#pragma unroll
  for (int k = 0; k < 4; ++k) {
    int i = tid + k * 256;
    twl[ZIDX(i)] = twg[i];
  }
  c32 sa = {0.f, 0.f}, sb = {0.f, 0.f}, s5 = {0.f, 0.f};
  const c32* pbase = part + (size_t)b * 32 * 513;
  for (int p = 0; p < 32; ++p) {
    const c32* pp = pbase + p * 513;
    sa = cadd(sa, pp[tid]);
    sb = cadd(sb, pp[tid + 256]);
    if (tid == 0) s5 = cadd(s5, pp[512]);
  }
  S[tid] = sa;
  S[tid + 256] = sb;
  if (tid == 0) S[512] = s5;
  if (tid > 0) S[1024 - tid] = c32{sa.x, -sa.y};  // 769..1023
  S[768 - tid] = c32{sb.x, -sb.y};                // 513..768
  __syncthreads();
#pragma unroll
  for (int k = 0; k < 4; ++k) {
    int t = tid + k * 256;
    zz[ZIDX(drev4(t))] = S[t];
  }
  __syncthreads();
  for (int s = 0; s < 5; ++s) {
    fft_stage<1>(&zz[0], twl, tid, s);
    __syncthreads();
  }
  const float scl = 1.0f / (1024.0f * 512.0f);  // irfft 1/N * mean over 512 dims
#pragma unroll
  for (int k = 0; k < 4; ++k) {
    int t = tid + k * 256;
    corr[t] = zz[ZIDX(t)].x * scl;
  }
  __syncthreads();
  __shared__ float swv[4];
  __shared__ int swi[4];
  __shared__ float selv[CTOPK];
  __shared__ int seli[CTOPK];
  int wid = tid >> 6, lane = tid & 63;
  for (int k = 0; k < CTOPK; ++k) {
    float bv = -INFINITY;
    int bi = 0;
#pragma unroll
    for (int q = 0; q < 4; ++q) {
      int idx = tid + q * 256;
      float v = corr[idx];
      if (v > bv || (v == bv && idx < bi)) { bv = v; bi = idx; }
    }
#pragma unroll
    for (int off = 32; off > 0; off >>= 1) {
      float ov = __shfl_down(bv, off);
      int oi = __shfl_down(bi, off);
      if (ov > bv || (ov == bv && oi < bi)) { bv = ov; bi = oi; }
    }
    if (lane == 0) { swv[wid] = bv; swi[wid] = bi; }
    __syncthreads();
    if (tid == 0) {
      float mvv = swv[0];
      int mi = swi[0];
      for (int q2 = 1; q2 < 4; ++q2)
        if (swv[q2] > mvv || (swv[q2] == mvv && swi[q2] < mi)) { mvv = swv[q2]; mi = swi[q2]; }
      selv[k] = mvv;
      seli[k] = mi;
      corr[mi] = -INFINITY;
    }
    __syncthreads();
  }
  if (tid == 0) {
    float mx = selv[0], sum = 0.f, e[CTOPK];
    for (int k = 0; k < CTOPK; ++k) {
      e[k] = expf(selv[k] - mx);
      sum += e[k];
    }
    float inv = 1.0f / sum;
    for (int k = 0; k < CTOPK; ++k) {
      wts[b * CTOPK + k] = e[k] * inv;
      idxs[b * CTOPK + k] = seli[k];
    }
  }
}

// ---------------- delay aggregation: bf16 V [Mc][512]; XCD-swizzled -----------------
__global__ __launch_bounds__(128) void k_agg(const ushort* __restrict__ Vf,
                                             const float* __restrict__ wts,
                                             const int* __restrict__ idxs,
                                             ushort* __restrict__ out2) {
  int nb = gridDim.x;
  int blk = blockIdx.x;
  int row = (blk & 7) * (nb >> 3) + (blk >> 3);
  int b = row >> 10, t = row & 1023;
  int d0 = threadIdx.x * 4;
  const ushort* Vb = Vf + (size_t)b * CT * 512;
  float4 acc = {0.f, 0.f, 0.f, 0.f};
#pragma unroll
  for (int k = 0; k < CTOPK; ++k) {
    float w = wts[b * CTOPK + k];
    int r = t + idxs[b * CTOPK + k];
    if (r >= CT) r -= CT;
    ushort4 v = *(const ushort4*)(Vb + (size_t)r * 512 + d0);
    acc.x += w * bf16f(v.x);
    acc.y += w * bf16f(v.y);
    acc.z += w * bf16f(v.z);
    acc.w += w * bf16f(v.w);
  }
  ushort4 hv = {bf16r(acc.x), bf16r(acc.y), bf16r(acc.z), bf16r(acc.w)};
  *(ushort4*)(out2 + (size_t)row * CD + d0) = hv;
}

// ---------------- fused LN + series decomp, SLIDING WINDOW --------------------------
__global__ __launch_bounds__(256) void k_dec2(const float* __restrict__ X,
                                              const c32* __restrict__ st,
                                              const float* __restrict__ g,
                                              float* __restrict__ out,
                                              ushort* __restrict__ out2) {
  int b = blockIdx.y;
  int t0 = blockIdx.x * 64;
  int tid = threadIdx.x;
  const float* xb = X + (size_t)b * CT * CD;
  const c32* sb = st + (size_t)b * CT;
  float g0v = g[tid], g1v = g[tid + 256];
  float s0 = 0.f, s1 = 0.f;
#pragma unroll
  for (int j = -12; j <= 12; ++j) {
    int u = t0 + j;
    u = u < 0 ? 0 : (u > CT - 1 ? CT - 1 : u);
    c32 ms = sb[u];
    s0 += (xb[(size_t)u * CD + tid] - ms.x) * ms.y;
    s1 += (xb[(size_t)u * CD + tid + 256] - ms.x) * ms.y;
  }
  const float inv = 1.0f / 25.0f;
  for (int tt = 0; tt < 64; ++tt) {
    int t = t0 + tt;
    c32 mc = sb[t];
    float z0 = (xb[(size_t)t * CD + tid] - mc.x) * mc.y;
    float z1 = (xb[(size_t)t * CD + tid + 256] - mc.x) * mc.y;
    float o0 = g0v * (z0 - s0 * inv);
    float o1 = g1v * (z1 - s1 * inv);
    size_t ro = (size_t)(b * CT + t) * CD;
    out[ro + tid] = o0;
    out[ro + tid + 256] = o1;
    out2[ro + tid] = bf16r(o0);
    out2[ro + tid + 256] = bf16r(o1);
    int ua = t + 13;
    ua = ua > CT - 1 ? CT - 1 : ua;
    int ur = t - 12;
    ur = ur < 0 ? 0 : ur;
    c32 ma = sb[ua], mr = sb[ur];
    s0 += (xb[(size_t)ua * CD + tid] - ma.x) * ma.y -
          (xb[(size_t)ur * CD + tid] - mr.x) * mr.y;
    s1 += (xb[(size_t)ua * CD + tid + 256] - ma.x) * ma.y -
          (xb[(size_t)ur * CD + tid + 256] - mr.x) * mr.y;
  }
}

// ---------------- partial time-mean: grid (Bc, 8), coalesced ------------------------
__global__ __launch_bounds__(256) void k_meanp(const float* __restrict__ X,
                                               float* __restrict__ part) {
  int b = blockIdx.x, g = blockIdx.y, tid = threadIdx.x;
  const float* xb = X + (size_t)b * CT * CD + (size_t)g * 128 * CD;
  float a0 = 0.f, a1 = 0.f;
  for (int r = 0; r < 128; ++r) {
    a0 += xb[(size_t)r * CD + tid];
    a1 += xb[(size_t)r * CD + tid + 256];
  }
  part[((size_t)b * 8 + g) * CD + tid] = a0;
  part[((size_t)b * 8 + g) * CD + tid + 256] = a1;
}

// ---------------- final head: mean-combine + 2-layer MLP ----------------------------
__global__ __launch_bounds__(256) void k_headf(const float* __restrict__ part,
                                               const float* __restrict__ w1,
                                               const float* __restrict__ b1,
                                               const float* __restrict__ w2,
                                               const float* __restrict__ b2,
                                               float* __restrict__ out) {
  int b = blockIdx.x, tid = threadIdx.x;
  __shared__ float f[CD];
  __shared__ float hid[CFCH];
  for (int d = tid; d < CD; d += 256) {
    float s = 0.f;
#pragma unroll
    for (int g = 0; g < 8; ++g) s += part[((size_t)b * 8 + g) * CD + d];
    f[d] = s * (1.0f / CT);
  }
  __syncthreads();
  float a = b1[tid];
  for (int d = 0; d < CD; ++d) a += f[d] * w1[d * CFCH + tid];
  hid[tid] = fmaxf(a, 0.f);
  __syncthreads();
  if (tid < CNC) {
    float a2 = b2[tid];
    for (int j = 0; j < CFCH; ++j) a2 += hid[j] * w2[j * CNC + tid];
    out[b * CNC + tid] = a2;
  }
}

// =====================================================================================
extern "C" void kernel_launch(void* const* d_in, const int* in_sizes, int n_in,
                              void* d_out, int out_size, void* d_ws, size_t ws_size,
                              hipStream_t stream) {
  const float* x = (const float*)d_in[0];
  const float* emb_w = (const float*)d_in[1];
  const float* emb_g = (const float*)d_in[2];
  const float* emb_b = (const float*)d_in[3];
  const float* attn_w = (const float*)d_in[4];
  const float* attn_b = (const float*)d_in[5];
  const float* ln_g = (const float*)d_in[6];
  const float* ln_bb = (const float*)d_in[7];
  const float* fc1_w = (const float*)d_in[8];
  const float* fc1_b = (const float*)d_in[9];
  const float* fc2_w = (const float*)d_in[10];
  const float* fc2_b = (const float*)d_in[11];
  const float* hw1 = (const float*)d_in[12];
  const float* hb1 = (const float*)d_in[13];
  const float* hw2 = (const float*)d_in[14];
  const float* hb2 = (const float*)d_in[15];
  float* outp = (float*)d_out;

  // per-layer bf16 weights (ushorts): wq,wk,wv (contig => fused QKV), wo, w1, w2
  const size_t WQ = 262144ULL;                         // 512*512
  const size_t LW = 4 * WQ + 1048576ULL + 1048576ULL;  // 3,145,728 ushorts
  const size_t W2TOT = CL * LW;

  const size_t FIXED_B = W2TOT * 2                     // bf16 weights
                         + (size_t)CT * CD * 4         // postab
                         + 2 * (size_t)CB * CCH * 4    // sc,lg
                         + 2 * (size_t)CB * CTOPK * 4  // wts,idxs
                         + (size_t)CB * 8 * CD * 4     // mean partials
                         + 1024 * 8                    // twiddles
                         + 4096;
  const size_t PERB = 2ULL * CT * CD * 4 + (size_t)CT * CD * 2 + (size_t)CT * 2048 * 2 +
                      (size_t)32 * 513 * 8 + (size_t)CT * 8 + (size_t)CT * 64;
  int Bc = CB;
  while (Bc > 1) {
    if ((size_t)Bc * PERB + FIXED_B <= ws_size) break;
    Bc >>= 1;
  }
  const size_t CHF = (size_t)Bc * CT * CD;

  char* wsp = (char*)d_ws;
  float* P0 = (float*)wsp;     wsp += CHF * 4;
  float* P1 = (float*)wsp;     wsp += CHF * 4;
  ushort* U0 = (ushort*)wsp;   wsp += CHF * 2;            // h2 / agg-out / d2
  ushort* U1 = (ushort*)wsp;   wsp += (size_t)Bc * CT * 2048 * 2;  // fp32 QT / bf16 f2
  ushort* W2b = (ushort*)wsp;  wsp += W2TOT * 2;
  float* postab = (float*)wsp; wsp += (size_t)CT * CD * 4;
  float* scb = (float*)wsp;    wsp += (size_t)CB * CCH * 4;
  float* lgb = (float*)wsp;    wsp += (size_t)CB * CCH * 4;
  float* wtb = (float*)wsp;    wsp += (size_t)CB * CTOPK * 4;
  int* idb = (int*)wsp;        wsp += (size_t)CB * CTOPK * 4;
  float* partb = (float*)wsp;  wsp += (size_t)CB * 8 * CD * 4;
  c32* twc = (c32*)wsp;        wsp += 1024 * sizeof(c32);
  c32* partc = (c32*)wsp;      wsp += (size_t)Bc * 32 * 513 * sizeof(c32);
  c32* stb = (c32*)wsp;        wsp += (size_t)Bc * CT * sizeof(c32);
  c32* st8b = (c32*)wsp;       wsp += (size_t)Bc * CT * 8 * sizeof(c32);

  // ---- convert all weights to transposed bf16 [N][K], once per call ----
  for (int l = 0; l < CL; ++l) {
    ushort* wq2 = W2b + l * LW;      // [1536][512] fused QKV (q,k,v contiguous)
    ushort* w12 = wq2 + 4 * WQ;
    ushort* w22 = w12 + 1048576;
    k_cvtw<<<dim3(CD / 32, CD / 32, 4), 256, 0, stream>>>(
        attn_w + (size_t)l * 4 * CD * CD, wq2, CD, CD);
    k_cvtw<<<dim3(CFFN / 32, CD / 32, 1), 256, 0, stream>>>(
        fc1_w + (size_t)l * CD * CFFN, w12, CD, CFFN);
    k_cvtw<<<dim3(CD / 32, CFFN / 32, 1), 256, 0, stream>>>(
        fc2_w + (size_t)l * CFFN * CD, w22, CFFN, CD);
  }

  k_scale<<<CB, 256, 0, stream>>>(x, scb, lgb);
  k_postab<<<CT, 512, 0, stream>>>(postab);
  k_twid<<<4, 256, 0, stream>>>(twc);

  for (int b0 = 0; b0 < CB; b0 += Bc) {
    const int Mc = Bc * CT;

    float* HP = P0;  // h fp32 (stable across layers; no swap needed)
    float* SA = P1;  // scratch: bf16 V / attn-out / ffn-out

    k_embed<<<Mc, 128, 0, stream>>>(x + (size_t)b0 * CT * CCH, scb + b0 * CCH,
                                    lgb + b0 * CCH, emb_w, postab, emb_g, emb_b,
                                    HP, U0);

    for (int l = 0; l < CL; ++l) {
      const float* bqkv = attn_b + (size_t)l * 4 * CD;  // q,k,v biases contiguous
      const float* bo = attn_b + (size_t)(l * 4 + 3) * CD;
      const float* g0 = ln_g + (size_t)(l * 2 + 0) * CD;
      const float* g1 = ln_g + (size_t)(l * 2 + 1) * CD;
      const float* B1 = fc1_b + (size_t)l * CFFN;
      const float* B2f = fc2_b + (size_t)l * CD;
      const ushort* wq2 = W2b + l * LW;
      const ushort* wo2 = wq2 + 3 * WQ;
      const ushort* w12 = wq2 + 4 * WQ;
      const ushort* w22 = w12 + 1048576;

      // fused QKV projection: fp32 Q,K TRANSPOSED -> U1 QT[1024][Mc]; bf16 V -> SA
      k_gemm3<7><<<dim3(1536 / 128, Mc / 128), 256, 0, stream>>>(
          U0, wq2, bqkv, nullptr, (float*)U1, (ushort*)SA, nullptr, CD, CD, Mc, CD);
      // packed-real FFT autocorrelation: product spectra -> partc
      k_fft<<<dim3(32, Bc), 256, 0, stream>>>((const float*)U1, twc, partc, Mc);
      // spectrum reduce + irfft + top-20 + softmax
      k_spectopk<<<Bc, 256, 0, stream>>>(partc, twc, wtb, idb);
      // delay aggregation (bf16 V in SA) -> U0 bf16
      k_agg<<<Mc, 128, 0, stream>>>((const ushort*)SA, wtb, idb, U0);
      // O proj (+residual HP) -> SA, with fused LN-stats partials
      k_gemm3<3><<<dim3(CD / 128, Mc / 128), 256, 0, stream>>>(
          U0, wo2, bo, HP, (float*)SA, nullptr, (ushort*)st8b, CD, CD, CD, CD);
      k_finst<<<Mc / 256, 256, 0, stream>>>(st8b, stb);
      k_dec2<<<dim3(CT / 64, Bc), 256, 0, stream>>>((float*)SA, stb, g0, HP, U0);
      // FFN: FC1 (GELU -> bf16 f2 = U1 [Mc][2048]), FC2 (+res HP, stats) -> SA
      k_gemm3<1><<<dim3(CFFN / 128, Mc / 128), 256, 0, stream>>>(
          U0, w12, B1, nullptr, nullptr, U1, nullptr, CD, CD, CFFN, CD);
      k_gemm3<3><<<dim3(CD / 128, Mc / 128), 256, 0, stream>>>(
          U1, w22, B2f, HP, (float*)SA, nullptr, (ushort*)st8b, CFFN, CFFN, CD, CFFN);
      k_finst<<<Mc / 256, 256, 0, stream>>>(st8b, stb);
      k_dec2<<<dim3(CT / 64, Bc), 256, 0, stream>>>((float*)SA, stb, g1, HP, U0);
    }

    k_meanp<<<dim3(Bc, 8), 256, 0, stream>>>(HP, partb + (size_t)b0 * 8 * CD);
    k_headf<<<Bc, 256, 0, stream>>>(partb + (size_t)b0 * 8 * CD, hw1, hb1, hw2, hb2,
                                    outp + (size_t)b0 * CNC);
  }
}